// Round 10
// baseline (1672.912 us; speedup 1.0000x reference)
//
#include <hip/hip_runtime.h>
#include <cstdint>

#define NEG_SLOPE 0.2f

__device__ __forceinline__ float leaky(float v) { return v > 0.f ? v : NEG_SLOPE * v; }
__device__ __forceinline__ float elu(float v) { return v > 0.f ? v : __expf(v) - 1.f; }

typedef _Float16 half2v __attribute__((ext_vector_type(2)));
union H8 { float4 f4; half2v h[4]; };   // 16 B = 8 halves
union H4 { float2 f2; half2v h[2]; };   // 8 B = 4 halves

// ---------------- CSR build (multi-dispatch; software grid barriers are ~4x
// slower than dispatch boundaries on MI355X — measured round 8) ----------------

__global__ void count_kernel(const int* __restrict__ dst, int* __restrict__ cnt, int E) {
    int i = blockIdx.x * blockDim.x + threadIdx.x;
    if (i < E) atomicAdd(&cnt[dst[i]], 1);
}

__global__ __launch_bounds__(256) void scanA_kernel(const int* __restrict__ cnt,
                                                    int* __restrict__ bsum, int n) {
    int base = blockIdx.x * 1024 + threadIdx.x * 4;
    int s = 0;
    if (base + 3 < n) {
        int4 v = *(const int4*)(cnt + base);
        s = v.x + v.y + v.z + v.w;
    } else {
        for (int j = 0; j < 4; ++j) if (base + j < n) s += cnt[base + j];
    }
#pragma unroll
    for (int o = 1; o < 64; o <<= 1) s += __shfl_xor(s, o);
    __shared__ int ws_[4];
    if ((threadIdx.x & 63) == 0) ws_[threadIdx.x >> 6] = s;
    __syncthreads();
    if (threadIdx.x == 0) bsum[blockIdx.x] = ws_[0] + ws_[1] + ws_[2] + ws_[3];
}

__global__ __launch_bounds__(1024) void scanB_kernel(int* __restrict__ bsum, int G) {
    __shared__ int sm[1024];
    int t = threadIdx.x;
    sm[t] = (t < G) ? bsum[t] : 0;
    __syncthreads();
    for (int o = 1; o < 1024; o <<= 1) {
        int u = (t >= o) ? sm[t - o] : 0;
        __syncthreads();
        sm[t] += u;
        __syncthreads();
    }
    if (t < G) bsum[t] = sm[t];
}

__global__ __launch_bounds__(256) void scanC_kernel(const int* __restrict__ cnt,
                                                    const int* __restrict__ bscan,
                                                    int* __restrict__ rp,
                                                    int* __restrict__ cur, int n) {
    int b = blockIdx.x, t = threadIdx.x;
    int base = b * 1024 + t * 4;
    int v[4]; int s = 0;
#pragma unroll
    for (int j = 0; j < 4; ++j) { int idx = base + j; v[j] = (idx < n) ? cnt[idx] : 0; s += v[j]; }
    int lane = t & 63;
    int x = s;
#pragma unroll
    for (int o = 1; o < 64; o <<= 1) { int u = __shfl_up(x, o); if (lane >= o) x += u; }
    __shared__ int wsum[4], woff[4];
    if (lane == 63) wsum[t >> 6] = x;
    __syncthreads();
    if (t == 0) { int a = 0; for (int i = 0; i < 4; ++i) { woff[i] = a; a += wsum[i]; } }
    __syncthreads();
    int off = ((b == 0) ? 0 : bscan[b - 1]) + (x - s) + woff[t >> 6];
#pragma unroll
    for (int j = 0; j < 4; ++j) {
        int idx = base + j;
        if (idx <= n) rp[idx] = off;
        if (idx < n) cur[idx] = off;
        off += v[j];
    }
}

__global__ void scatter_kernel(const int* __restrict__ src, const int* __restrict__ dst,
                               int* __restrict__ cur, int* __restrict__ col, int E) {
    int i = blockIdx.x * blockDim.x + threadIdx.x;
    if (i < E) {
        int pos = atomicAdd(&cur[dst[i]], 1);
        col[pos] = src[i];
    }
}

// ---------------- GEMM1: h1 = x @ W1 (fp16 out) + fused alpha dots ----------------
// Round-10 restructure: 64x64 tile (2 col-blocks), BK=32 K-chunks, x staged
// TRANSPOSED (xT[k][row], pad 76 keeps b128 alignment) so per-k LDS is
// 3x ds_read_b128 instead of 8x ds_read_b32. LDS 18 KB/block (was 66 KB) ->
// grid-limited ~6 blocks/CU instead of LDS-limited 2.

__global__ __launch_bounds__(128) void gemm1_kernel(const float* __restrict__ x,
                                                    const float* __restrict__ W,
                                                    const float* __restrict__ a_src,
                                                    const float* __restrict__ a_dst,
                                                    _Float16* __restrict__ h1h,
                                                    float* __restrict__ as1,
                                                    float* __restrict__ ad1, int n) {
    __shared__ float xT[32 * 76];     // [k][row], row-padded to 76
    __shared__ float Wl[32 * 64];     // [k][col]
    int tid = threadIdx.x;
    int rb = blockIdx.x >> 1, cb = blockIdx.x & 1;
    int row0 = rb * 64;
    int r0 = (tid >> 4) * 8, c0 = (tid & 15) * 4;

    float4 acc[8];
#pragma unroll
    for (int r = 0; r < 8; ++r) acc[r] = make_float4(0.f, 0.f, 0.f, 0.f);

    const float4* W4 = (const float4*)W;
    for (int kc = 0; kc < 128; kc += 32) {
        __syncthreads();
        // stage x chunk transposed: 64 rows x 32 k
#pragma unroll
        for (int i = 0; i < 4; ++i) {
            int idx = tid + i * 128;          // float4 index: row*8 + kq
            int row = idx >> 3, kq = idx & 7;
            float4 v = make_float4(0.f, 0.f, 0.f, 0.f);
            if (row0 + row < n)
                v = *(const float4*)(x + (size_t)(row0 + row) * 128 + kc + kq * 4);
            xT[(kq * 4 + 0) * 76 + row] = v.x;
            xT[(kq * 4 + 1) * 76 + row] = v.y;
            xT[(kq * 4 + 2) * 76 + row] = v.z;
            xT[(kq * 4 + 3) * 76 + row] = v.w;
        }
        // stage W chunk: 32 k x 64 cols
#pragma unroll
        for (int i = 0; i < 4; ++i) {
            int idx = tid + i * 128;          // float4 index: k*16 + c4
            int k = idx >> 4, c4 = idx & 15;
            ((float4*)Wl)[k * 16 + c4] = W4[(kc + k) * 32 + cb * 16 + c4];
        }
        __syncthreads();
        for (int k = 0; k < 32; ++k) {
            float4 xa = *(float4*)&xT[k * 76 + r0];
            float4 xb = *(float4*)&xT[k * 76 + r0 + 4];
            float4 w  = *(float4*)&Wl[k * 64 + c0];
            acc[0].x += xa.x * w.x; acc[0].y += xa.x * w.y; acc[0].z += xa.x * w.z; acc[0].w += xa.x * w.w;
            acc[1].x += xa.y * w.x; acc[1].y += xa.y * w.y; acc[1].z += xa.y * w.z; acc[1].w += xa.y * w.w;
            acc[2].x += xa.z * w.x; acc[2].y += xa.z * w.y; acc[2].z += xa.z * w.z; acc[2].w += xa.z * w.w;
            acc[3].x += xa.w * w.x; acc[3].y += xa.w * w.y; acc[3].z += xa.w * w.z; acc[3].w += xa.w * w.w;
            acc[4].x += xb.x * w.x; acc[4].y += xb.x * w.y; acc[4].z += xb.x * w.z; acc[4].w += xb.x * w.w;
            acc[5].x += xb.y * w.x; acc[5].y += xb.y * w.y; acc[5].z += xb.y * w.z; acc[5].w += xb.y * w.w;
            acc[6].x += xb.z * w.x; acc[6].y += xb.z * w.y; acc[6].z += xb.z * w.z; acc[6].w += xb.z * w.w;
            acc[7].x += xb.w * w.x; acc[7].y += xb.w * w.y; acc[7].z += xb.w * w.z; acc[7].w += xb.w * w.w;
        }
    }
    // epilogue: fp16 store + fused alpha dots. global col = cb*64 + c0,
    // head h = cb*2 + (c0>>5), within-head col = c0 & 31.
    int h = cb * 2 + (c0 >> 5);
    int cc = c0 & 31;
    float asv[4], adv[4];
#pragma unroll
    for (int j = 0; j < 4; ++j) {
        asv[j] = a_src[h * 32 + cc + j];
        adv[j] = a_dst[h * 32 + cc + j];
    }
#pragma unroll
    for (int r = 0; r < 8; ++r) {
        int row = row0 + r0 + r;
        float4 a = acc[r];
        float ps = a.x * asv[0] + a.y * asv[1] + a.z * asv[2] + a.w * asv[3];
        float pd = a.x * adv[0] + a.y * adv[1] + a.z * adv[2] + a.w * adv[3];
#pragma unroll
        for (int o = 1; o < 8; o <<= 1) {
            ps += __shfl_xor(ps, o); pd += __shfl_xor(pd, o);
        }
        if (row < n) {
            H4 u;
            u.h[0] = half2v{(_Float16)a.x, (_Float16)a.y};
            u.h[1] = half2v{(_Float16)a.z, (_Float16)a.w};
            *(float2*)&h1h[(size_t)row * 128 + cb * 64 + c0] = u.f2;
            if ((tid & 7) == 0) {
                as1[row * 4 + h] = ps;
                ad1[row * 4 + h] = pd;
            }
        }
    }
}

// ---------------- GEMM2: h2 = hp @ W2 (fp16 in/out) + fused alpha dots ----------------

__global__ __launch_bounds__(256) void gemm2_kernel(const _Float16* __restrict__ hph,
                                                    const float* __restrict__ W2,
                                                    const float* __restrict__ a_src,
                                                    const float* __restrict__ a_dst,
                                                    _Float16* __restrict__ h2h,
                                                    float* __restrict__ as2,
                                                    float* __restrict__ ad2, int n) {
    __shared__ float Wl[128 * 32];
    __shared__ float xl[32][129];
    int tid = threadIdx.x;
    const float4* W4 = (const float4*)W2;
    float4* Wl4 = (float4*)Wl;
#pragma unroll
    for (int i = 0; i < 4; ++i) Wl4[tid + i * 256] = W4[tid + i * 256];
    int row0 = blockIdx.x * 32;
    for (int f = tid; f < 32 * 128; f += 256) {
        int r = f >> 7, k = f & 127;
        int row = row0 + r;
        xl[r][k] = (row < n) ? (float)hph[(size_t)row * 128 + k] : 0.f;
    }
    __syncthreads();
    int cg = tid & 7, r = tid >> 3;
    int c0 = cg * 4;
    float a0 = 0, a1 = 0, a2 = 0, a3 = 0;
    for (int k = 0; k < 128; ++k) {
        float4 w = *(const float4*)&Wl[k * 32 + c0];
        float xv = xl[r][k];
        a0 += xv * w.x; a1 += xv * w.y; a2 += xv * w.z; a3 += xv * w.w;
    }
    float ps = a0 * a_src[c0] + a1 * a_src[c0 + 1] + a2 * a_src[c0 + 2] + a3 * a_src[c0 + 3];
    float pd = a0 * a_dst[c0] + a1 * a_dst[c0 + 1] + a2 * a_dst[c0 + 2] + a3 * a_dst[c0 + 3];
#pragma unroll
    for (int o = 1; o < 8; o <<= 1) { ps += __shfl_xor(ps, o); pd += __shfl_xor(pd, o); }
    int row = row0 + r;
    if (row < n) {
        H4 u;
        u.h[0] = half2v{(_Float16)a0, (_Float16)a1};
        u.h[1] = half2v{(_Float16)a2, (_Float16)a3};
        *(float2*)&h2h[(size_t)row * 32 + c0] = u.f2;
        if (cg == 0) { as2[row] = ps; ad2[row] = pd; }
    }
}

// ---------------- layer-1 softmax + aggregate: wave/node, fp16 gather ----------------

__global__ __launch_bounds__(256) void agg1_kernel(const _Float16* __restrict__ h1h,
                                                   const float4* __restrict__ as1,
                                                   const float4* __restrict__ ad1,
                                                   const int* __restrict__ rp,
                                                   const int* __restrict__ col,
                                                   const float* __restrict__ b1,
                                                   _Float16* __restrict__ hph, int n) {
    __shared__ float4 s_p[4][64];
    int wave = threadIdx.x >> 6, lane = threadIdx.x & 63;
    int nid = blockIdx.x * 4 + wave;
    if (nid >= n) return;
    int start = rp[nid], end = rp[nid + 1];
    float4 adn = ad1[nid], asn = as1[nid];
    float4 psf;
    psf.x = __expf(leaky(asn.x + adn.x));
    psf.y = __expf(leaky(asn.y + adn.y));
    psf.z = __expf(leaky(asn.z + adn.z));
    psf.w = __expf(leaky(asn.w + adn.w));
    float4 dsum = make_float4(0.f, 0.f, 0.f, 0.f);
    int g = lane & 7, sub = lane >> 3;
    float4 aL0 = make_float4(0.f, 0.f, 0.f, 0.f);
    float4 aL1 = aL0, aH0 = aL0, aH1 = aL0;

    for (int base = start; base < end; base += 64) {
        int i = base + lane;
        int sidx = 0;
        float4 p = make_float4(0.f, 0.f, 0.f, 0.f);
        if (i < end) {
            sidx = col[i];
            float4 a = as1[sidx];
            p.x = __expf(leaky(a.x + adn.x));
            p.y = __expf(leaky(a.y + adn.y));
            p.z = __expf(leaky(a.z + adn.z));
            p.w = __expf(leaky(a.w + adn.w));
            dsum.x += p.x; dsum.y += p.y; dsum.z += p.z; dsum.w += p.w;
        }
        s_p[wave][lane] = p;         // intra-wave LDS, program order per wave
        int len = min(64, end - base);
        int steps = (len + 7) >> 3;  // wave-uniform
        for (int s = 0; s < steps; ++s) {
            int j = s * 8 + sub;
            int js = (j < len) ? j : 0;
            int rj = __shfl(sidx, js);           // all 64 lanes active
            if (j < len) {
                float4 pv = s_p[wave][js];
                float wl = (g < 4) ? pv.x : pv.y;
                float wh = (g < 4) ? pv.z : pv.w;
                const H8* row = (const H8*)(h1h + (size_t)rj * 128);
                H8 u0 = row[g], u1 = row[8 + g];
                aL0.x += (float)u0.h[0].x * wl; aL0.y += (float)u0.h[0].y * wl;
                aL0.z += (float)u0.h[1].x * wl; aL0.w += (float)u0.h[1].y * wl;
                aL1.x += (float)u0.h[2].x * wl; aL1.y += (float)u0.h[2].y * wl;
                aL1.z += (float)u0.h[3].x * wl; aL1.w += (float)u0.h[3].y * wl;
                aH0.x += (float)u1.h[0].x * wh; aH0.y += (float)u1.h[0].y * wh;
                aH0.z += (float)u1.h[1].x * wh; aH0.w += (float)u1.h[1].y * wh;
                aH1.x += (float)u1.h[2].x * wh; aH1.y += (float)u1.h[2].y * wh;
                aH1.z += (float)u1.h[3].x * wh; aH1.w += (float)u1.h[3].y * wh;
            }
        }
    }
    // self loop (one edge-subset adds it)
    if (sub == 0) {
        float wl = (g < 4) ? psf.x : psf.y;
        float wh = (g < 4) ? psf.z : psf.w;
        const H8* row = (const H8*)(h1h + (size_t)nid * 128);
        H8 u0 = row[g], u1 = row[8 + g];
        aL0.x += (float)u0.h[0].x * wl; aL0.y += (float)u0.h[0].y * wl;
        aL0.z += (float)u0.h[1].x * wl; aL0.w += (float)u0.h[1].y * wl;
        aL1.x += (float)u0.h[2].x * wl; aL1.y += (float)u0.h[2].y * wl;
        aL1.z += (float)u0.h[3].x * wl; aL1.w += (float)u0.h[3].y * wl;
        aH0.x += (float)u1.h[0].x * wh; aH0.y += (float)u1.h[0].y * wh;
        aH0.z += (float)u1.h[1].x * wh; aH0.w += (float)u1.h[1].y * wh;
        aH1.x += (float)u1.h[2].x * wh; aH1.y += (float)u1.h[2].y * wh;
        aH1.z += (float)u1.h[3].x * wh; aH1.w += (float)u1.h[3].y * wh;
    }
    if (lane == 0) {
        dsum.x += psf.x; dsum.y += psf.y; dsum.z += psf.z; dsum.w += psf.w;
    }
#pragma unroll
    for (int o = 1; o < 64; o <<= 1) {
        dsum.x += __shfl_xor(dsum.x, o); dsum.y += __shfl_xor(dsum.y, o);
        dsum.z += __shfl_xor(dsum.z, o); dsum.w += __shfl_xor(dsum.w, o);
    }
#pragma unroll
    for (int o = 8; o < 64; o <<= 1) {    // reduce over edge subsets (same g)
        aL0.x += __shfl_xor(aL0.x, o); aL0.y += __shfl_xor(aL0.y, o);
        aL0.z += __shfl_xor(aL0.z, o); aL0.w += __shfl_xor(aL0.w, o);
        aL1.x += __shfl_xor(aL1.x, o); aL1.y += __shfl_xor(aL1.y, o);
        aL1.z += __shfl_xor(aL1.z, o); aL1.w += __shfl_xor(aL1.w, o);
        aH0.x += __shfl_xor(aH0.x, o); aH0.y += __shfl_xor(aH0.y, o);
        aH0.z += __shfl_xor(aH0.z, o); aH0.w += __shfl_xor(aH0.w, o);
        aH1.x += __shfl_xor(aH1.x, o); aH1.y += __shfl_xor(aH1.y, o);
        aH1.z += __shfl_xor(aH1.z, o); aH1.w += __shfl_xor(aH1.w, o);
    }
    if (sub == 0) {
        float i0 = __builtin_amdgcn_rcpf(dsum.x);
        float i1 = __builtin_amdgcn_rcpf(dsum.y);
        float i2 = __builtin_amdgcn_rcpf(dsum.z);
        float i3 = __builtin_amdgcn_rcpf(dsum.w);
        float il = (g < 4) ? i0 : i1;
        float ih = (g < 4) ? i2 : i3;
        const float4* b4 = (const float4*)b1;
        float4 bL0 = b4[g * 2], bL1 = b4[g * 2 + 1];
        float4 bH0 = b4[16 + g * 2], bH1 = b4[16 + g * 2 + 1];
        float4 r0 = make_float4(elu(aL0.x * il + bL0.x), elu(aL0.y * il + bL0.y),
                                elu(aL0.z * il + bL0.z), elu(aL0.w * il + bL0.w));
        float4 r1 = make_float4(elu(aL1.x * il + bL1.x), elu(aL1.y * il + bL1.y),
                                elu(aL1.z * il + bL1.z), elu(aL1.w * il + bL1.w));
        float4 r2 = make_float4(elu(aH0.x * ih + bH0.x), elu(aH0.y * ih + bH0.y),
                                elu(aH0.z * ih + bH0.z), elu(aH0.w * ih + bH0.w));
        float4 r3 = make_float4(elu(aH1.x * ih + bH1.x), elu(aH1.y * ih + bH1.y),
                                elu(aH1.z * ih + bH1.z), elu(aH1.w * ih + bH1.w));
        H8 oL, oH;
        oL.h[0] = half2v{(_Float16)r0.x, (_Float16)r0.y};
        oL.h[1] = half2v{(_Float16)r0.z, (_Float16)r0.w};
        oL.h[2] = half2v{(_Float16)r1.x, (_Float16)r1.y};
        oL.h[3] = half2v{(_Float16)r1.z, (_Float16)r1.w};
        oH.h[0] = half2v{(_Float16)r2.x, (_Float16)r2.y};
        oH.h[1] = half2v{(_Float16)r2.z, (_Float16)r2.w};
        oH.h[2] = half2v{(_Float16)r3.x, (_Float16)r3.y};
        oH.h[3] = half2v{(_Float16)r3.z, (_Float16)r3.w};
        *(float4*)&hph[(size_t)nid * 128 + g * 8] = oL.f4;
        *(float4*)&hph[(size_t)nid * 128 + 64 + g * 8] = oH.f4;
    }
}

// ---------------- layer-2 softmax + aggregate: wave/node, fp16 gather ----------------

__global__ __launch_bounds__(256) void agg2_kernel(const _Float16* __restrict__ h2h,
                                                   const float* __restrict__ as2,
                                                   const float* __restrict__ ad2,
                                                   const int* __restrict__ rp,
                                                   const int* __restrict__ col,
                                                   const float* __restrict__ b2,
                                                   float* __restrict__ out, int n) {
    int wave = threadIdx.x >> 6, lane = threadIdx.x & 63;
    int nid = blockIdx.x * 4 + wave;
    if (nid >= n) return;
    int start = rp[nid], end = rp[nid + 1];
    float adn = ad2[nid];
    float psf = __expf(leaky(as2[nid] + adn));
    float dsum = 0.f;
    int g = lane & 7, sub = lane >> 3;
    float4 acc = make_float4(0.f, 0.f, 0.f, 0.f);
    for (int base = start; base < end; base += 64) {
        int i = base + lane;
        int sidx = 0;
        float p = 0.f;
        if (i < end) {
            sidx = col[i];
            p = __expf(leaky(as2[sidx] + adn));
            dsum += p;
        }
        int len = min(64, end - base);
        int steps = (len + 7) >> 3;
        for (int s = 0; s < steps; ++s) {
            int j = s * 8 + sub;
            int js = (j < len) ? j : 0;
            int rj = __shfl(sidx, js);
            float pj = __shfl(p, js);
            if (j < len) {
                H4 u = ((const H4*)(h2h + (size_t)rj * 32))[g];
                acc.x += (float)u.h[0].x * pj; acc.y += (float)u.h[0].y * pj;
                acc.z += (float)u.h[1].x * pj; acc.w += (float)u.h[1].y * pj;
            }
        }
    }
    if (sub == 0) {
        H4 u = ((const H4*)(h2h + (size_t)nid * 32))[g];
        acc.x += (float)u.h[0].x * psf; acc.y += (float)u.h[0].y * psf;
        acc.z += (float)u.h[1].x * psf; acc.w += (float)u.h[1].y * psf;
    }
    if (lane == 0) dsum += psf;
#pragma unroll
    for (int o = 1; o < 64; o <<= 1) dsum += __shfl_xor(dsum, o);
#pragma unroll
    for (int o = 8; o < 64; o <<= 1) {
        acc.x += __shfl_xor(acc.x, o); acc.y += __shfl_xor(acc.y, o);
        acc.z += __shfl_xor(acc.z, o); acc.w += __shfl_xor(acc.w, o);
    }
    if (sub == 0) {
        float inv = __builtin_amdgcn_rcpf(dsum);
        float4 bb = ((const float4*)b2)[g];
        ((float4*)(out + (size_t)nid * 32))[g] =
            make_float4(acc.x * inv + bb.x, acc.y * inv + bb.y,
                        acc.z * inv + bb.z, acc.w * inv + bb.w);
    }
}

// ---------------- launch ----------------

extern "C" void kernel_launch(void* const* d_in, const int* in_sizes, int n_in,
                              void* d_out, int out_size, void* d_ws, size_t ws_size,
                              hipStream_t stream) {
    const float* x      = (const float*)d_in[0];
    const int*   ei     = (const int*)d_in[1];
    const float* W1     = (const float*)d_in[2];
    const float* a_src1 = (const float*)d_in[3];
    const float* a_dst1 = (const float*)d_in[4];
    const float* b1     = (const float*)d_in[5];
    const float* W2     = (const float*)d_in[6];
    const float* a_src2 = (const float*)d_in[7];
    const float* a_dst2 = (const float*)d_in[8];
    const float* b2     = (const float*)d_in[9];
    float* out = (float*)d_out;

    const int N = in_sizes[0] / 128;
    const int E = in_sizes[1] / 2;
    const int* src = ei;
    const int* dstp = ei + E;

    uint8_t* w = (uint8_t*)d_ws;
    auto carve = [&](size_t bytes) {
        uint8_t* p = w;
        w += (bytes + 255) & ~(size_t)255;
        return p;
    };
    _Float16* h1h = (_Float16*)carve((size_t)N * 128 * 2);
    _Float16* hph = (_Float16*)carve((size_t)N * 128 * 2);
    _Float16* h2h = (_Float16*)carve((size_t)N * 32 * 2);
    float* as1 = (float*)carve((size_t)N * 4 * 4);
    float* ad1 = (float*)carve((size_t)N * 4 * 4);
    float* as2 = (float*)carve((size_t)N * 4);
    float* ad2 = (float*)carve((size_t)N * 4);
    int* rp   = (int*)carve((size_t)(N + 1) * 4);
    int* cnt  = (int*)carve((size_t)N * 4);
    int* cur  = (int*)carve((size_t)N * 4);
    int* col  = (int*)carve((size_t)E * 4);
    int* bsum = (int*)carve(1024 * 4);

    const int G = (N + 1023) / 1024;   // <= 1024

    // CSR build (multi-dispatch)
    hipMemsetAsync(cnt, 0, (size_t)N * 4, stream);
    count_kernel<<<(E + 255) / 256, 256, 0, stream>>>(dstp, cnt, E);
    scanA_kernel<<<G, 256, 0, stream>>>(cnt, bsum, N);
    scanB_kernel<<<1, 1024, 0, stream>>>(bsum, G);
    scanC_kernel<<<G, 256, 0, stream>>>(cnt, bsum, rp, cur, N);
    scatter_kernel<<<(E + 255) / 256, 256, 0, stream>>>(src, dstp, cur, col, E);

    // layer 1
    gemm1_kernel<<<2 * ((N + 63) / 64), 128, 0, stream>>>(x, W1, a_src1, a_dst1,
                                                          h1h, as1, ad1, N);
    agg1_kernel<<<(N + 3) / 4, 256, 0, stream>>>(h1h, (const float4*)as1, (const float4*)ad1,
                                                 rp, col, b1, hph, N);
    // layer 2
    gemm2_kernel<<<(N + 31) / 32, 256, 0, stream>>>(hph, W2, a_src2, a_dst2, h2h, as2, ad2, N);
    agg2_kernel<<<(N + 3) / 4, 256, 0, stream>>>(h2h, as2, ad2, rp, col, b2, out, N);
}

// Round 11
// 311.738 us; speedup vs baseline: 5.3664x; 5.3664x over previous
//
#include <hip/hip_runtime.h>
#include <cstdint>

#define NEG_SLOPE 0.2f

__device__ __forceinline__ float leaky(float v) { return v > 0.f ? v : NEG_SLOPE * v; }
__device__ __forceinline__ float elu(float v) { return v > 0.f ? v : __expf(v) - 1.f; }

typedef _Float16 half2v __attribute__((ext_vector_type(2)));
union H8 { float4 f4; half2v h[4]; };   // 16 B = 8 halves
union H4 { float2 f2; half2v h[2]; };   // 8 B = 4 halves

// ---------------- CSR build (multi-dispatch; software grid barriers are ~4x
// slower than dispatch boundaries on MI355X — measured round 8) ----------------

__global__ void count_kernel(const int* __restrict__ dst, int* __restrict__ cnt, int E) {
    int i = blockIdx.x * blockDim.x + threadIdx.x;
    if (i < E) atomicAdd(&cnt[dst[i]], 1);
}

__global__ __launch_bounds__(256) void scanA_kernel(const int* __restrict__ cnt,
                                                    int* __restrict__ bsum, int n) {
    int base = blockIdx.x * 1024 + threadIdx.x * 4;
    int s = 0;
    if (base + 3 < n) {
        int4 v = *(const int4*)(cnt + base);
        s = v.x + v.y + v.z + v.w;
    } else {
        for (int j = 0; j < 4; ++j) if (base + j < n) s += cnt[base + j];
    }
#pragma unroll
    for (int o = 1; o < 64; o <<= 1) s += __shfl_xor(s, o);
    __shared__ int ws_[4];
    if ((threadIdx.x & 63) == 0) ws_[threadIdx.x >> 6] = s;
    __syncthreads();
    if (threadIdx.x == 0) bsum[blockIdx.x] = ws_[0] + ws_[1] + ws_[2] + ws_[3];
}

__global__ __launch_bounds__(1024) void scanB_kernel(int* __restrict__ bsum, int G) {
    __shared__ int sm[1024];
    int t = threadIdx.x;
    sm[t] = (t < G) ? bsum[t] : 0;
    __syncthreads();
    for (int o = 1; o < 1024; o <<= 1) {
        int u = (t >= o) ? sm[t - o] : 0;
        __syncthreads();
        sm[t] += u;
        __syncthreads();
    }
    if (t < G) bsum[t] = sm[t];
}

__global__ __launch_bounds__(256) void scanC_kernel(const int* __restrict__ cnt,
                                                    const int* __restrict__ bscan,
                                                    int* __restrict__ rp,
                                                    int* __restrict__ cur, int n) {
    int b = blockIdx.x, t = threadIdx.x;
    int base = b * 1024 + t * 4;
    int v[4]; int s = 0;
#pragma unroll
    for (int j = 0; j < 4; ++j) { int idx = base + j; v[j] = (idx < n) ? cnt[idx] : 0; s += v[j]; }
    int lane = t & 63;
    int x = s;
#pragma unroll
    for (int o = 1; o < 64; o <<= 1) { int u = __shfl_up(x, o); if (lane >= o) x += u; }
    __shared__ int wsum[4], woff[4];
    if (lane == 63) wsum[t >> 6] = x;
    __syncthreads();
    if (t == 0) { int a = 0; for (int i = 0; i < 4; ++i) { woff[i] = a; a += wsum[i]; } }
    __syncthreads();
    int off = ((b == 0) ? 0 : bscan[b - 1]) + (x - s) + woff[t >> 6];
#pragma unroll
    for (int j = 0; j < 4; ++j) {
        int idx = base + j;
        if (idx <= n) rp[idx] = off;
        if (idx < n) cur[idx] = off;
        off += v[j];
    }
}

__global__ void scatter_kernel(const int* __restrict__ src, const int* __restrict__ dst,
                               int* __restrict__ cur, int* __restrict__ col, int E) {
    int i = blockIdx.x * blockDim.x + threadIdx.x;
    if (i < E) {
        int pos = atomicAdd(&cur[dst[i]], 1);
        col[pos] = src[i];
    }
}

// ---------------- GEMM1: h1 = x @ W1 (fp16 out) + fused alpha dots ----------------
// 64x64 tile (2 col-blocks), BK=32 K-chunks, x staged transposed.
// Round-11 fix: __launch_bounds__(128,4) caps VGPR at 128 (round 10 hit 256 + a
// 2.8 GB/dispatch scratch-spill storm); unroll 1 on kc stops cross-chunk load
// hoisting; unroll 8 on k bounds the ds_read window.

__global__ __launch_bounds__(128, 4) void gemm1_kernel(const float* __restrict__ x,
                                                       const float* __restrict__ W,
                                                       const float* __restrict__ a_src,
                                                       const float* __restrict__ a_dst,
                                                       _Float16* __restrict__ h1h,
                                                       float* __restrict__ as1,
                                                       float* __restrict__ ad1, int n) {
    __shared__ float xT[32 * 76];     // [k][row], row-padded to 76
    __shared__ float Wl[32 * 64];     // [k][col]
    int tid = threadIdx.x;
    int rb = blockIdx.x >> 1, cb = blockIdx.x & 1;
    int row0 = rb * 64;
    int r0 = (tid >> 4) * 8, c0 = (tid & 15) * 4;

    float4 acc[8];
#pragma unroll
    for (int r = 0; r < 8; ++r) acc[r] = make_float4(0.f, 0.f, 0.f, 0.f);

    const float4* W4 = (const float4*)W;
#pragma unroll 1
    for (int kc = 0; kc < 128; kc += 32) {
        __syncthreads();
        // stage x chunk transposed: 64 rows x 32 k
#pragma unroll
        for (int i = 0; i < 4; ++i) {
            int idx = tid + i * 128;          // float4 index: row*8 + kq
            int row = idx >> 3, kq = idx & 7;
            float4 v = make_float4(0.f, 0.f, 0.f, 0.f);
            if (row0 + row < n)
                v = *(const float4*)(x + (size_t)(row0 + row) * 128 + kc + kq * 4);
            xT[(kq * 4 + 0) * 76 + row] = v.x;
            xT[(kq * 4 + 1) * 76 + row] = v.y;
            xT[(kq * 4 + 2) * 76 + row] = v.z;
            xT[(kq * 4 + 3) * 76 + row] = v.w;
        }
        // stage W chunk: 32 k x 64 cols
#pragma unroll
        for (int i = 0; i < 4; ++i) {
            int idx = tid + i * 128;          // float4 index: k*16 + c4
            int k = idx >> 4, c4 = idx & 15;
            ((float4*)Wl)[k * 16 + c4] = W4[(kc + k) * 32 + cb * 16 + c4];
        }
        __syncthreads();
#pragma unroll 8
        for (int k = 0; k < 32; ++k) {
            float4 xa = *(float4*)&xT[k * 76 + r0];
            float4 xb = *(float4*)&xT[k * 76 + r0 + 4];
            float4 w  = *(float4*)&Wl[k * 64 + c0];
            acc[0].x += xa.x * w.x; acc[0].y += xa.x * w.y; acc[0].z += xa.x * w.z; acc[0].w += xa.x * w.w;
            acc[1].x += xa.y * w.x; acc[1].y += xa.y * w.y; acc[1].z += xa.y * w.z; acc[1].w += xa.y * w.w;
            acc[2].x += xa.z * w.x; acc[2].y += xa.z * w.y; acc[2].z += xa.z * w.z; acc[2].w += xa.z * w.w;
            acc[3].x += xa.w * w.x; acc[3].y += xa.w * w.y; acc[3].z += xa.w * w.z; acc[3].w += xa.w * w.w;
            acc[4].x += xb.x * w.x; acc[4].y += xb.x * w.y; acc[4].z += xb.x * w.z; acc[4].w += xb.x * w.w;
            acc[5].x += xb.y * w.x; acc[5].y += xb.y * w.y; acc[5].z += xb.y * w.z; acc[5].w += xb.y * w.w;
            acc[6].x += xb.z * w.x; acc[6].y += xb.z * w.y; acc[6].z += xb.z * w.z; acc[6].w += xb.z * w.w;
            acc[7].x += xb.w * w.x; acc[7].y += xb.w * w.y; acc[7].z += xb.w * w.z; acc[7].w += xb.w * w.w;
        }
    }
    // epilogue: fp16 store + fused alpha dots. global col = cb*64 + c0,
    // head h = cb*2 + (c0>>5), within-head col = c0 & 31.
    int h = cb * 2 + (c0 >> 5);
    int cc = c0 & 31;
    float asv[4], adv[4];
#pragma unroll
    for (int j = 0; j < 4; ++j) {
        asv[j] = a_src[h * 32 + cc + j];
        adv[j] = a_dst[h * 32 + cc + j];
    }
#pragma unroll
    for (int r = 0; r < 8; ++r) {
        int row = row0 + r0 + r;
        float4 a = acc[r];
        float ps = a.x * asv[0] + a.y * asv[1] + a.z * asv[2] + a.w * asv[3];
        float pd = a.x * adv[0] + a.y * adv[1] + a.z * adv[2] + a.w * adv[3];
#pragma unroll
        for (int o = 1; o < 8; o <<= 1) {
            ps += __shfl_xor(ps, o); pd += __shfl_xor(pd, o);
        }
        if (row < n) {
            H4 u;
            u.h[0] = half2v{(_Float16)a.x, (_Float16)a.y};
            u.h[1] = half2v{(_Float16)a.z, (_Float16)a.w};
            *(float2*)&h1h[(size_t)row * 128 + cb * 64 + c0] = u.f2;
            if ((tid & 7) == 0) {
                as1[row * 4 + h] = ps;
                ad1[row * 4 + h] = pd;
            }
        }
    }
}

// ---------------- GEMM2: h2 = hp @ W2 (fp16 in/out) + fused alpha dots ----------------

__global__ __launch_bounds__(256) void gemm2_kernel(const _Float16* __restrict__ hph,
                                                    const float* __restrict__ W2,
                                                    const float* __restrict__ a_src,
                                                    const float* __restrict__ a_dst,
                                                    _Float16* __restrict__ h2h,
                                                    float* __restrict__ as2,
                                                    float* __restrict__ ad2, int n) {
    __shared__ float Wl[128 * 32];
    __shared__ float xl[32][129];
    int tid = threadIdx.x;
    const float4* W4 = (const float4*)W2;
    float4* Wl4 = (float4*)Wl;
#pragma unroll
    for (int i = 0; i < 4; ++i) Wl4[tid + i * 256] = W4[tid + i * 256];
    int row0 = blockIdx.x * 32;
    for (int f = tid; f < 32 * 128; f += 256) {
        int r = f >> 7, k = f & 127;
        int row = row0 + r;
        xl[r][k] = (row < n) ? (float)hph[(size_t)row * 128 + k] : 0.f;
    }
    __syncthreads();
    int cg = tid & 7, r = tid >> 3;
    int c0 = cg * 4;
    float a0 = 0, a1 = 0, a2 = 0, a3 = 0;
    for (int k = 0; k < 128; ++k) {
        float4 w = *(const float4*)&Wl[k * 32 + c0];
        float xv = xl[r][k];
        a0 += xv * w.x; a1 += xv * w.y; a2 += xv * w.z; a3 += xv * w.w;
    }
    float ps = a0 * a_src[c0] + a1 * a_src[c0 + 1] + a2 * a_src[c0 + 2] + a3 * a_src[c0 + 3];
    float pd = a0 * a_dst[c0] + a1 * a_dst[c0 + 1] + a2 * a_dst[c0 + 2] + a3 * a_dst[c0 + 3];
#pragma unroll
    for (int o = 1; o < 8; o <<= 1) { ps += __shfl_xor(ps, o); pd += __shfl_xor(pd, o); }
    int row = row0 + r;
    if (row < n) {
        H4 u;
        u.h[0] = half2v{(_Float16)a0, (_Float16)a1};
        u.h[1] = half2v{(_Float16)a2, (_Float16)a3};
        *(float2*)&h2h[(size_t)row * 32 + c0] = u.f2;
        if (cg == 0) { as2[row] = ps; ad2[row] = pd; }
    }
}

// ---------------- layer-1 softmax + aggregate: wave/node, fp16 gather ----------------

__global__ __launch_bounds__(256) void agg1_kernel(const _Float16* __restrict__ h1h,
                                                   const float4* __restrict__ as1,
                                                   const float4* __restrict__ ad1,
                                                   const int* __restrict__ rp,
                                                   const int* __restrict__ col,
                                                   const float* __restrict__ b1,
                                                   _Float16* __restrict__ hph, int n) {
    __shared__ float4 s_p[4][64];
    int wave = threadIdx.x >> 6, lane = threadIdx.x & 63;
    int nid = blockIdx.x * 4 + wave;
    if (nid >= n) return;
    int start = rp[nid], end = rp[nid + 1];
    float4 adn = ad1[nid], asn = as1[nid];
    float4 psf;
    psf.x = __expf(leaky(asn.x + adn.x));
    psf.y = __expf(leaky(asn.y + adn.y));
    psf.z = __expf(leaky(asn.z + adn.z));
    psf.w = __expf(leaky(asn.w + adn.w));
    float4 dsum = make_float4(0.f, 0.f, 0.f, 0.f);
    int g = lane & 7, sub = lane >> 3;
    float4 aL0 = make_float4(0.f, 0.f, 0.f, 0.f);
    float4 aL1 = aL0, aH0 = aL0, aH1 = aL0;

    for (int base = start; base < end; base += 64) {
        int i = base + lane;
        int sidx = 0;
        float4 p = make_float4(0.f, 0.f, 0.f, 0.f);
        if (i < end) {
            sidx = col[i];
            float4 a = as1[sidx];
            p.x = __expf(leaky(a.x + adn.x));
            p.y = __expf(leaky(a.y + adn.y));
            p.z = __expf(leaky(a.z + adn.z));
            p.w = __expf(leaky(a.w + adn.w));
            dsum.x += p.x; dsum.y += p.y; dsum.z += p.z; dsum.w += p.w;
        }
        s_p[wave][lane] = p;         // intra-wave LDS, program order per wave
        int len = min(64, end - base);
        int steps = (len + 7) >> 3;  // wave-uniform
        for (int s = 0; s < steps; ++s) {
            int j = s * 8 + sub;
            int js = (j < len) ? j : 0;
            int rj = __shfl(sidx, js);           // all 64 lanes active
            if (j < len) {
                float4 pv = s_p[wave][js];
                float wl = (g < 4) ? pv.x : pv.y;
                float wh = (g < 4) ? pv.z : pv.w;
                const H8* row = (const H8*)(h1h + (size_t)rj * 128);
                H8 u0 = row[g], u1 = row[8 + g];
                aL0.x += (float)u0.h[0].x * wl; aL0.y += (float)u0.h[0].y * wl;
                aL0.z += (float)u0.h[1].x * wl; aL0.w += (float)u0.h[1].y * wl;
                aL1.x += (float)u0.h[2].x * wl; aL1.y += (float)u0.h[2].y * wl;
                aL1.z += (float)u0.h[3].x * wl; aL1.w += (float)u0.h[3].y * wl;
                aH0.x += (float)u1.h[0].x * wh; aH0.y += (float)u1.h[0].y * wh;
                aH0.z += (float)u1.h[1].x * wh; aH0.w += (float)u1.h[1].y * wh;
                aH1.x += (float)u1.h[2].x * wh; aH1.y += (float)u1.h[2].y * wh;
                aH1.z += (float)u1.h[3].x * wh; aH1.w += (float)u1.h[3].y * wh;
            }
        }
    }
    // self loop (one edge-subset adds it)
    if (sub == 0) {
        float wl = (g < 4) ? psf.x : psf.y;
        float wh = (g < 4) ? psf.z : psf.w;
        const H8* row = (const H8*)(h1h + (size_t)nid * 128);
        H8 u0 = row[g], u1 = row[8 + g];
        aL0.x += (float)u0.h[0].x * wl; aL0.y += (float)u0.h[0].y * wl;
        aL0.z += (float)u0.h[1].x * wl; aL0.w += (float)u0.h[1].y * wl;
        aL1.x += (float)u0.h[2].x * wl; aL1.y += (float)u0.h[2].y * wl;
        aL1.z += (float)u0.h[3].x * wl; aL1.w += (float)u0.h[3].y * wl;
        aH0.x += (float)u1.h[0].x * wh; aH0.y += (float)u1.h[0].y * wh;
        aH0.z += (float)u1.h[1].x * wh; aH0.w += (float)u1.h[1].y * wh;
        aH1.x += (float)u1.h[2].x * wh; aH1.y += (float)u1.h[2].y * wh;
        aH1.z += (float)u1.h[3].x * wh; aH1.w += (float)u1.h[3].y * wh;
    }
    if (lane == 0) {
        dsum.x += psf.x; dsum.y += psf.y; dsum.z += psf.z; dsum.w += psf.w;
    }
#pragma unroll
    for (int o = 1; o < 64; o <<= 1) {
        dsum.x += __shfl_xor(dsum.x, o); dsum.y += __shfl_xor(dsum.y, o);
        dsum.z += __shfl_xor(dsum.z, o); dsum.w += __shfl_xor(dsum.w, o);
    }
#pragma unroll
    for (int o = 8; o < 64; o <<= 1) {    // reduce over edge subsets (same g)
        aL0.x += __shfl_xor(aL0.x, o); aL0.y += __shfl_xor(aL0.y, o);
        aL0.z += __shfl_xor(aL0.z, o); aL0.w += __shfl_xor(aL0.w, o);
        aL1.x += __shfl_xor(aL1.x, o); aL1.y += __shfl_xor(aL1.y, o);
        aL1.z += __shfl_xor(aL1.z, o); aL1.w += __shfl_xor(aL1.w, o);
        aH0.x += __shfl_xor(aH0.x, o); aH0.y += __shfl_xor(aH0.y, o);
        aH0.z += __shfl_xor(aH0.z, o); aH0.w += __shfl_xor(aH0.w, o);
        aH1.x += __shfl_xor(aH1.x, o); aH1.y += __shfl_xor(aH1.y, o);
        aH1.z += __shfl_xor(aH1.z, o); aH1.w += __shfl_xor(aH1.w, o);
    }
    if (sub == 0) {
        float i0 = __builtin_amdgcn_rcpf(dsum.x);
        float i1 = __builtin_amdgcn_rcpf(dsum.y);
        float i2 = __builtin_amdgcn_rcpf(dsum.z);
        float i3 = __builtin_amdgcn_rcpf(dsum.w);
        float il = (g < 4) ? i0 : i1;
        float ih = (g < 4) ? i2 : i3;
        const float4* b4 = (const float4*)b1;
        float4 bL0 = b4[g * 2], bL1 = b4[g * 2 + 1];
        float4 bH0 = b4[16 + g * 2], bH1 = b4[16 + g * 2 + 1];
        float4 r0 = make_float4(elu(aL0.x * il + bL0.x), elu(aL0.y * il + bL0.y),
                                elu(aL0.z * il + bL0.z), elu(aL0.w * il + bL0.w));
        float4 r1 = make_float4(elu(aL1.x * il + bL1.x), elu(aL1.y * il + bL1.y),
                                elu(aL1.z * il + bL1.z), elu(aL1.w * il + bL1.w));
        float4 r2 = make_float4(elu(aH0.x * ih + bH0.x), elu(aH0.y * ih + bH0.y),
                                elu(aH0.z * ih + bH0.z), elu(aH0.w * ih + bH0.w));
        float4 r3 = make_float4(elu(aH1.x * ih + bH1.x), elu(aH1.y * ih + bH1.y),
                                elu(aH1.z * ih + bH1.z), elu(aH1.w * ih + bH1.w));
        H8 oL, oH;
        oL.h[0] = half2v{(_Float16)r0.x, (_Float16)r0.y};
        oL.h[1] = half2v{(_Float16)r0.z, (_Float16)r0.w};
        oL.h[2] = half2v{(_Float16)r1.x, (_Float16)r1.y};
        oL.h[3] = half2v{(_Float16)r1.z, (_Float16)r1.w};
        oH.h[0] = half2v{(_Float16)r2.x, (_Float16)r2.y};
        oH.h[1] = half2v{(_Float16)r2.z, (_Float16)r2.w};
        oH.h[2] = half2v{(_Float16)r3.x, (_Float16)r3.y};
        oH.h[3] = half2v{(_Float16)r3.z, (_Float16)r3.w};
        *(float4*)&hph[(size_t)nid * 128 + g * 8] = oL.f4;
        *(float4*)&hph[(size_t)nid * 128 + 64 + g * 8] = oH.f4;
    }
}

// ---------------- layer-2 softmax + aggregate: wave/node, fp16 gather ----------------

__global__ __launch_bounds__(256) void agg2_kernel(const _Float16* __restrict__ h2h,
                                                   const float* __restrict__ as2,
                                                   const float* __restrict__ ad2,
                                                   const int* __restrict__ rp,
                                                   const int* __restrict__ col,
                                                   const float* __restrict__ b2,
                                                   float* __restrict__ out, int n) {
    int wave = threadIdx.x >> 6, lane = threadIdx.x & 63;
    int nid = blockIdx.x * 4 + wave;
    if (nid >= n) return;
    int start = rp[nid], end = rp[nid + 1];
    float adn = ad2[nid];
    float psf = __expf(leaky(as2[nid] + adn));
    float dsum = 0.f;
    int g = lane & 7, sub = lane >> 3;
    float4 acc = make_float4(0.f, 0.f, 0.f, 0.f);
    for (int base = start; base < end; base += 64) {
        int i = base + lane;
        int sidx = 0;
        float p = 0.f;
        if (i < end) {
            sidx = col[i];
            p = __expf(leaky(as2[sidx] + adn));
            dsum += p;
        }
        int len = min(64, end - base);
        int steps = (len + 7) >> 3;
        for (int s = 0; s < steps; ++s) {
            int j = s * 8 + sub;
            int js = (j < len) ? j : 0;
            int rj = __shfl(sidx, js);
            float pj = __shfl(p, js);
            if (j < len) {
                H4 u = ((const H4*)(h2h + (size_t)rj * 32))[g];
                acc.x += (float)u.h[0].x * pj; acc.y += (float)u.h[0].y * pj;
                acc.z += (float)u.h[1].x * pj; acc.w += (float)u.h[1].y * pj;
            }
        }
    }
    if (sub == 0) {
        H4 u = ((const H4*)(h2h + (size_t)nid * 32))[g];
        acc.x += (float)u.h[0].x * psf; acc.y += (float)u.h[0].y * psf;
        acc.z += (float)u.h[1].x * psf; acc.w += (float)u.h[1].y * psf;
    }
    if (lane == 0) dsum += psf;
#pragma unroll
    for (int o = 1; o < 64; o <<= 1) dsum += __shfl_xor(dsum, o);
#pragma unroll
    for (int o = 8; o < 64; o <<= 1) {
        acc.x += __shfl_xor(acc.x, o); acc.y += __shfl_xor(acc.y, o);
        acc.z += __shfl_xor(acc.z, o); acc.w += __shfl_xor(acc.w, o);
    }
    if (sub == 0) {
        float inv = __builtin_amdgcn_rcpf(dsum);
        float4 bb = ((const float4*)b2)[g];
        ((float4*)(out + (size_t)nid * 32))[g] =
            make_float4(acc.x * inv + bb.x, acc.y * inv + bb.y,
                        acc.z * inv + bb.z, acc.w * inv + bb.w);
    }
}

// ---------------- launch ----------------

extern "C" void kernel_launch(void* const* d_in, const int* in_sizes, int n_in,
                              void* d_out, int out_size, void* d_ws, size_t ws_size,
                              hipStream_t stream) {
    const float* x      = (const float*)d_in[0];
    const int*   ei     = (const int*)d_in[1];
    const float* W1     = (const float*)d_in[2];
    const float* a_src1 = (const float*)d_in[3];
    const float* a_dst1 = (const float*)d_in[4];
    const float* b1     = (const float*)d_in[5];
    const float* W2     = (const float*)d_in[6];
    const float* a_src2 = (const float*)d_in[7];
    const float* a_dst2 = (const float*)d_in[8];
    const float* b2     = (const float*)d_in[9];
    float* out = (float*)d_out;

    const int N = in_sizes[0] / 128;
    const int E = in_sizes[1] / 2;
    const int* src = ei;
    const int* dstp = ei + E;

    uint8_t* w = (uint8_t*)d_ws;
    auto carve = [&](size_t bytes) {
        uint8_t* p = w;
        w += (bytes + 255) & ~(size_t)255;
        return p;
    };
    _Float16* h1h = (_Float16*)carve((size_t)N * 128 * 2);
    _Float16* hph = (_Float16*)carve((size_t)N * 128 * 2);
    _Float16* h2h = (_Float16*)carve((size_t)N * 32 * 2);
    float* as1 = (float*)carve((size_t)N * 4 * 4);
    float* ad1 = (float*)carve((size_t)N * 4 * 4);
    float* as2 = (float*)carve((size_t)N * 4);
    float* ad2 = (float*)carve((size_t)N * 4);
    int* rp   = (int*)carve((size_t)(N + 1) * 4);
    int* cnt  = (int*)carve((size_t)N * 4);
    int* cur  = (int*)carve((size_t)N * 4);
    int* col  = (int*)carve((size_t)E * 4);
    int* bsum = (int*)carve(1024 * 4);

    const int G = (N + 1023) / 1024;   // <= 1024

    // CSR build (multi-dispatch)
    hipMemsetAsync(cnt, 0, (size_t)N * 4, stream);
    count_kernel<<<(E + 255) / 256, 256, 0, stream>>>(dstp, cnt, E);
    scanA_kernel<<<G, 256, 0, stream>>>(cnt, bsum, N);
    scanB_kernel<<<1, 1024, 0, stream>>>(bsum, G);
    scanC_kernel<<<G, 256, 0, stream>>>(cnt, bsum, rp, cur, N);
    scatter_kernel<<<(E + 255) / 256, 256, 0, stream>>>(src, dstp, cur, col, E);

    // layer 1
    gemm1_kernel<<<2 * ((N + 63) / 64), 128, 0, stream>>>(x, W1, a_src1, a_dst1,
                                                          h1h, as1, ad1, N);
    agg1_kernel<<<(N + 3) / 4, 256, 0, stream>>>(h1h, (const float4*)as1, (const float4*)ad1,
                                                 rp, col, b1, hph, N);
    // layer 2
    gemm2_kernel<<<(N + 31) / 32, 256, 0, stream>>>(hph, W2, a_src2, a_dst2, h2h, as2, ad2, N);
    agg2_kernel<<<(N + 3) / 4, 256, 0, stream>>>(h2h, as2, ad2, rp, col, b2, out, N);
}

// Round 12
// 309.155 us; speedup vs baseline: 5.4112x; 1.0084x over previous
//
#include <hip/hip_runtime.h>
#include <cstdint>

#define NEG_SLOPE 0.2f

__device__ __forceinline__ float leaky(float v) { return v > 0.f ? v : NEG_SLOPE * v; }
__device__ __forceinline__ float elu(float v) { return v > 0.f ? v : __expf(v) - 1.f; }

typedef _Float16 half2v __attribute__((ext_vector_type(2)));
union H8 { float4 f4; half2v h[4]; };   // 16 B = 8 halves
union H4 { float2 f2; half2v h[2]; };   // 8 B = 4 halves

// ---------------- single-block scan (round-1 proven): cnt -> rp ----------------

__global__ __launch_bounds__(1024) void scan_kernel(const int* __restrict__ cnt,
                                                    int* __restrict__ rp, int n) {
    __shared__ int part[1024];
    int tid = threadIdx.x;
    int chunk = (n + 1023) >> 10;
    int beg = tid * chunk;
    int end = min(beg + chunk, n);
    int s = 0;
    for (int i = beg; i < end; ++i) s += cnt[i];
    part[tid] = s;
    __syncthreads();
    for (int off = 1; off < 1024; off <<= 1) {
        int v = (tid >= off) ? part[tid - off] : 0;
        __syncthreads();
        part[tid] += v;
        __syncthreads();
    }
    int prefix = (tid == 0) ? 0 : part[tid - 1];
    for (int i = beg; i < end; ++i) { rp[i] = prefix; prefix += cnt[i]; }
    if (tid == 1023) rp[n] = part[1023];
}

// ---------------- scatter (rank-based, atomic-free) ----------------

__global__ void scatter_kernel(const int* __restrict__ src, const int* __restrict__ dstp,
                               const int* __restrict__ rp, const int* __restrict__ ranks,
                               int* __restrict__ col, int E) {
    int i = blockIdx.x * blockDim.x + threadIdx.x;
    if (i < E) col[rp[dstp[i]] + ranks[i]] = src[i];
}

// ---------------- fused GEMM1 + edge count ----------------
// Blocks [0, gemmBlocks): h1 = x @ W1 (fp16 out) + fused alpha dots.
// Blocks [gemmBlocks, ...): in-degree count, storing per-edge rank (atomicAdd
// return) so the scatter pass needs no atomics. Independent work fused into one
// dispatch so count's atomic latency hides under gemm compute.

__global__ __launch_bounds__(128, 4) void gemm1_count_kernel(
        const float* __restrict__ x, const float* __restrict__ W,
        const float* __restrict__ a_src, const float* __restrict__ a_dst,
        _Float16* __restrict__ h1h, float* __restrict__ as1, float* __restrict__ ad1,
        int n, int gemmBlocks,
        const int* __restrict__ dstp, int* __restrict__ cnt, int* __restrict__ ranks, int E) {
    if ((int)blockIdx.x >= gemmBlocks) {
        int i = ((int)blockIdx.x - gemmBlocks) * 128 + threadIdx.x;
        if (i < E) ranks[i] = atomicAdd(&cnt[dstp[i]], 1);
        return;
    }
    __shared__ float xT[32 * 76];     // [k][row], row-padded to 76
    __shared__ float Wl[32 * 64];     // [k][col]
    int tid = threadIdx.x;
    int rb = blockIdx.x >> 1, cb = blockIdx.x & 1;
    int row0 = rb * 64;
    int r0 = (tid >> 4) * 8, c0 = (tid & 15) * 4;

    float4 acc[8];
#pragma unroll
    for (int r = 0; r < 8; ++r) acc[r] = make_float4(0.f, 0.f, 0.f, 0.f);

    const float4* W4 = (const float4*)W;
#pragma unroll 1
    for (int kc = 0; kc < 128; kc += 32) {
        __syncthreads();
        // stage x chunk transposed: 64 rows x 32 k
#pragma unroll
        for (int i = 0; i < 4; ++i) {
            int idx = tid + i * 128;          // float4 index: row*8 + kq
            int row = idx >> 3, kq = idx & 7;
            float4 v = make_float4(0.f, 0.f, 0.f, 0.f);
            if (row0 + row < n)
                v = *(const float4*)(x + (size_t)(row0 + row) * 128 + kc + kq * 4);
            xT[(kq * 4 + 0) * 76 + row] = v.x;
            xT[(kq * 4 + 1) * 76 + row] = v.y;
            xT[(kq * 4 + 2) * 76 + row] = v.z;
            xT[(kq * 4 + 3) * 76 + row] = v.w;
        }
        // stage W chunk: 32 k x 64 cols
#pragma unroll
        for (int i = 0; i < 4; ++i) {
            int idx = tid + i * 128;          // float4 index: k*16 + c4
            int k = idx >> 4, c4 = idx & 15;
            ((float4*)Wl)[k * 16 + c4] = W4[(kc + k) * 32 + cb * 16 + c4];
        }
        __syncthreads();
#pragma unroll 8
        for (int k = 0; k < 32; ++k) {
            float4 xa = *(float4*)&xT[k * 76 + r0];
            float4 xb = *(float4*)&xT[k * 76 + r0 + 4];
            float4 w  = *(float4*)&Wl[k * 64 + c0];
            acc[0].x += xa.x * w.x; acc[0].y += xa.x * w.y; acc[0].z += xa.x * w.z; acc[0].w += xa.x * w.w;
            acc[1].x += xa.y * w.x; acc[1].y += xa.y * w.y; acc[1].z += xa.y * w.z; acc[1].w += xa.y * w.w;
            acc[2].x += xa.z * w.x; acc[2].y += xa.z * w.y; acc[2].z += xa.z * w.z; acc[2].w += xa.z * w.w;
            acc[3].x += xa.w * w.x; acc[3].y += xa.w * w.y; acc[3].z += xa.w * w.z; acc[3].w += xa.w * w.w;
            acc[4].x += xb.x * w.x; acc[4].y += xb.x * w.y; acc[4].z += xb.x * w.z; acc[4].w += xb.x * w.w;
            acc[5].x += xb.y * w.x; acc[5].y += xb.y * w.y; acc[5].z += xb.y * w.z; acc[5].w += xb.y * w.w;
            acc[6].x += xb.z * w.x; acc[6].y += xb.z * w.y; acc[6].z += xb.z * w.z; acc[6].w += xb.z * w.w;
            acc[7].x += xb.w * w.x; acc[7].y += xb.w * w.y; acc[7].z += xb.w * w.z; acc[7].w += xb.w * w.w;
        }
    }
    // epilogue: fp16 store + fused alpha dots. global col = cb*64 + c0,
    // head h = cb*2 + (c0>>5), within-head col = c0 & 31.
    int h = cb * 2 + (c0 >> 5);
    int cc = c0 & 31;
    float asv[4], adv[4];
#pragma unroll
    for (int j = 0; j < 4; ++j) {
        asv[j] = a_src[h * 32 + cc + j];
        adv[j] = a_dst[h * 32 + cc + j];
    }
#pragma unroll
    for (int r = 0; r < 8; ++r) {
        int row = row0 + r0 + r;
        float4 a = acc[r];
        float ps = a.x * asv[0] + a.y * asv[1] + a.z * asv[2] + a.w * asv[3];
        float pd = a.x * adv[0] + a.y * adv[1] + a.z * adv[2] + a.w * adv[3];
#pragma unroll
        for (int o = 1; o < 8; o <<= 1) {
            ps += __shfl_xor(ps, o); pd += __shfl_xor(pd, o);
        }
        if (row < n) {
            H4 u;
            u.h[0] = half2v{(_Float16)a.x, (_Float16)a.y};
            u.h[1] = half2v{(_Float16)a.z, (_Float16)a.w};
            *(float2*)&h1h[(size_t)row * 128 + cb * 64 + c0] = u.f2;
            if ((tid & 7) == 0) {
                as1[row * 4 + h] = ps;
                ad1[row * 4 + h] = pd;
            }
        }
    }
}

// ---------------- GEMM2: h2 = hp @ W2 (fp16 in/out) + fused alpha dots ----------------

__global__ __launch_bounds__(256) void gemm2_kernel(const _Float16* __restrict__ hph,
                                                    const float* __restrict__ W2,
                                                    const float* __restrict__ a_src,
                                                    const float* __restrict__ a_dst,
                                                    _Float16* __restrict__ h2h,
                                                    float* __restrict__ as2,
                                                    float* __restrict__ ad2, int n) {
    __shared__ float Wl[128 * 32];
    __shared__ float xl[32][129];
    int tid = threadIdx.x;
    const float4* W4 = (const float4*)W2;
    float4* Wl4 = (float4*)Wl;
#pragma unroll
    for (int i = 0; i < 4; ++i) Wl4[tid + i * 256] = W4[tid + i * 256];
    int row0 = blockIdx.x * 32;
    for (int f = tid; f < 32 * 128; f += 256) {
        int r = f >> 7, k = f & 127;
        int row = row0 + r;
        xl[r][k] = (row < n) ? (float)hph[(size_t)row * 128 + k] : 0.f;
    }
    __syncthreads();
    int cg = tid & 7, r = tid >> 3;
    int c0 = cg * 4;
    float a0 = 0, a1 = 0, a2 = 0, a3 = 0;
    for (int k = 0; k < 128; ++k) {
        float4 w = *(const float4*)&Wl[k * 32 + c0];
        float xv = xl[r][k];
        a0 += xv * w.x; a1 += xv * w.y; a2 += xv * w.z; a3 += xv * w.w;
    }
    float ps = a0 * a_src[c0] + a1 * a_src[c0 + 1] + a2 * a_src[c0 + 2] + a3 * a_src[c0 + 3];
    float pd = a0 * a_dst[c0] + a1 * a_dst[c0 + 1] + a2 * a_dst[c0 + 2] + a3 * a_dst[c0 + 3];
#pragma unroll
    for (int o = 1; o < 8; o <<= 1) { ps += __shfl_xor(ps, o); pd += __shfl_xor(pd, o); }
    int row = row0 + r;
    if (row < n) {
        H4 u;
        u.h[0] = half2v{(_Float16)a0, (_Float16)a1};
        u.h[1] = half2v{(_Float16)a2, (_Float16)a3};
        *(float2*)&h2h[(size_t)row * 32 + c0] = u.f2;
        if (cg == 0) { as2[row] = ps; ad2[row] = pd; }
    }
}

// ---------------- layer-1 softmax + aggregate: wave/node, fp16 gather ----------------

__global__ __launch_bounds__(256) void agg1_kernel(const _Float16* __restrict__ h1h,
                                                   const float4* __restrict__ as1,
                                                   const float4* __restrict__ ad1,
                                                   const int* __restrict__ rp,
                                                   const int* __restrict__ col,
                                                   const float* __restrict__ b1,
                                                   _Float16* __restrict__ hph, int n) {
    __shared__ float4 s_p[4][64];
    int wave = threadIdx.x >> 6, lane = threadIdx.x & 63;
    int nid = blockIdx.x * 4 + wave;
    if (nid >= n) return;
    int start = rp[nid], end = rp[nid + 1];
    float4 adn = ad1[nid], asn = as1[nid];
    float4 psf;
    psf.x = __expf(leaky(asn.x + adn.x));
    psf.y = __expf(leaky(asn.y + adn.y));
    psf.z = __expf(leaky(asn.z + adn.z));
    psf.w = __expf(leaky(asn.w + adn.w));
    float4 dsum = make_float4(0.f, 0.f, 0.f, 0.f);
    int g = lane & 7, sub = lane >> 3;
    float4 aL0 = make_float4(0.f, 0.f, 0.f, 0.f);
    float4 aL1 = aL0, aH0 = aL0, aH1 = aL0;

    for (int base = start; base < end; base += 64) {
        int i = base + lane;
        int sidx = 0;
        float4 p = make_float4(0.f, 0.f, 0.f, 0.f);
        if (i < end) {
            sidx = col[i];
            float4 a = as1[sidx];
            p.x = __expf(leaky(a.x + adn.x));
            p.y = __expf(leaky(a.y + adn.y));
            p.z = __expf(leaky(a.z + adn.z));
            p.w = __expf(leaky(a.w + adn.w));
            dsum.x += p.x; dsum.y += p.y; dsum.z += p.z; dsum.w += p.w;
        }
        s_p[wave][lane] = p;         // intra-wave LDS, program order per wave
        int len = min(64, end - base);
        int steps = (len + 7) >> 3;  // wave-uniform
        for (int s = 0; s < steps; ++s) {
            int j = s * 8 + sub;
            int js = (j < len) ? j : 0;
            int rj = __shfl(sidx, js);           // all 64 lanes active
            if (j < len) {
                float4 pv = s_p[wave][js];
                float wl = (g < 4) ? pv.x : pv.y;
                float wh = (g < 4) ? pv.z : pv.w;
                const H8* row = (const H8*)(h1h + (size_t)rj * 128);
                H8 u0 = row[g], u1 = row[8 + g];
                aL0.x += (float)u0.h[0].x * wl; aL0.y += (float)u0.h[0].y * wl;
                aL0.z += (float)u0.h[1].x * wl; aL0.w += (float)u0.h[1].y * wl;
                aL1.x += (float)u0.h[2].x * wl; aL1.y += (float)u0.h[2].y * wl;
                aL1.z += (float)u0.h[3].x * wl; aL1.w += (float)u0.h[3].y * wl;
                aH0.x += (float)u1.h[0].x * wh; aH0.y += (float)u1.h[0].y * wh;
                aH0.z += (float)u1.h[1].x * wh; aH0.w += (float)u1.h[1].y * wh;
                aH1.x += (float)u1.h[2].x * wh; aH1.y += (float)u1.h[2].y * wh;
                aH1.z += (float)u1.h[3].x * wh; aH1.w += (float)u1.h[3].y * wh;
            }
        }
    }
    // self loop (one edge-subset adds it)
    if (sub == 0) {
        float wl = (g < 4) ? psf.x : psf.y;
        float wh = (g < 4) ? psf.z : psf.w;
        const H8* row = (const H8*)(h1h + (size_t)nid * 128);
        H8 u0 = row[g], u1 = row[8 + g];
        aL0.x += (float)u0.h[0].x * wl; aL0.y += (float)u0.h[0].y * wl;
        aL0.z += (float)u0.h[1].x * wl; aL0.w += (float)u0.h[1].y * wl;
        aL1.x += (float)u0.h[2].x * wl; aL1.y += (float)u0.h[2].y * wl;
        aL1.z += (float)u0.h[3].x * wl; aL1.w += (float)u0.h[3].y * wl;
        aH0.x += (float)u1.h[0].x * wh; aH0.y += (float)u1.h[0].y * wh;
        aH0.z += (float)u1.h[1].x * wh; aH0.w += (float)u1.h[1].y * wh;
        aH1.x += (float)u1.h[2].x * wh; aH1.y += (float)u1.h[2].y * wh;
        aH1.z += (float)u1.h[3].x * wh; aH1.w += (float)u1.h[3].y * wh;
    }
    if (lane == 0) {
        dsum.x += psf.x; dsum.y += psf.y; dsum.z += psf.z; dsum.w += psf.w;
    }
#pragma unroll
    for (int o = 1; o < 64; o <<= 1) {
        dsum.x += __shfl_xor(dsum.x, o); dsum.y += __shfl_xor(dsum.y, o);
        dsum.z += __shfl_xor(dsum.z, o); dsum.w += __shfl_xor(dsum.w, o);
    }
#pragma unroll
    for (int o = 8; o < 64; o <<= 1) {    // reduce over edge subsets (same g)
        aL0.x += __shfl_xor(aL0.x, o); aL0.y += __shfl_xor(aL0.y, o);
        aL0.z += __shfl_xor(aL0.z, o); aL0.w += __shfl_xor(aL0.w, o);
        aL1.x += __shfl_xor(aL1.x, o); aL1.y += __shfl_xor(aL1.y, o);
        aL1.z += __shfl_xor(aL1.z, o); aL1.w += __shfl_xor(aL1.w, o);
        aH0.x += __shfl_xor(aH0.x, o); aH0.y += __shfl_xor(aH0.y, o);
        aH0.z += __shfl_xor(aH0.z, o); aH0.w += __shfl_xor(aH0.w, o);
        aH1.x += __shfl_xor(aH1.x, o); aH1.y += __shfl_xor(aH1.y, o);
        aH1.z += __shfl_xor(aH1.z, o); aH1.w += __shfl_xor(aH1.w, o);
    }
    if (sub == 0) {
        float i0 = __builtin_amdgcn_rcpf(dsum.x);
        float i1 = __builtin_amdgcn_rcpf(dsum.y);
        float i2 = __builtin_amdgcn_rcpf(dsum.z);
        float i3 = __builtin_amdgcn_rcpf(dsum.w);
        float il = (g < 4) ? i0 : i1;
        float ih = (g < 4) ? i2 : i3;
        const float4* b4 = (const float4*)b1;
        float4 bL0 = b4[g * 2], bL1 = b4[g * 2 + 1];
        float4 bH0 = b4[16 + g * 2], bH1 = b4[16 + g * 2 + 1];
        float4 r0 = make_float4(elu(aL0.x * il + bL0.x), elu(aL0.y * il + bL0.y),
                                elu(aL0.z * il + bL0.z), elu(aL0.w * il + bL0.w));
        float4 r1 = make_float4(elu(aL1.x * il + bL1.x), elu(aL1.y * il + bL1.y),
                                elu(aL1.z * il + bL1.z), elu(aL1.w * il + bL1.w));
        float4 r2 = make_float4(elu(aH0.x * ih + bH0.x), elu(aH0.y * ih + bH0.y),
                                elu(aH0.z * ih + bH0.z), elu(aH0.w * ih + bH0.w));
        float4 r3 = make_float4(elu(aH1.x * ih + bH1.x), elu(aH1.y * ih + bH1.y),
                                elu(aH1.z * ih + bH1.z), elu(aH1.w * ih + bH1.w));
        H8 oL, oH;
        oL.h[0] = half2v{(_Float16)r0.x, (_Float16)r0.y};
        oL.h[1] = half2v{(_Float16)r0.z, (_Float16)r0.w};
        oL.h[2] = half2v{(_Float16)r1.x, (_Float16)r1.y};
        oL.h[3] = half2v{(_Float16)r1.z, (_Float16)r1.w};
        oH.h[0] = half2v{(_Float16)r2.x, (_Float16)r2.y};
        oH.h[1] = half2v{(_Float16)r2.z, (_Float16)r2.w};
        oH.h[2] = half2v{(_Float16)r3.x, (_Float16)r3.y};
        oH.h[3] = half2v{(_Float16)r3.z, (_Float16)r3.w};
        *(float4*)&hph[(size_t)nid * 128 + g * 8] = oL.f4;
        *(float4*)&hph[(size_t)nid * 128 + 64 + g * 8] = oH.f4;
    }
}

// ---------------- layer-2 softmax + aggregate: wave/node, fp16 gather ----------------

__global__ __launch_bounds__(256) void agg2_kernel(const _Float16* __restrict__ h2h,
                                                   const float* __restrict__ as2,
                                                   const float* __restrict__ ad2,
                                                   const int* __restrict__ rp,
                                                   const int* __restrict__ col,
                                                   const float* __restrict__ b2,
                                                   float* __restrict__ out, int n) {
    int wave = threadIdx.x >> 6, lane = threadIdx.x & 63;
    int nid = blockIdx.x * 4 + wave;
    if (nid >= n) return;
    int start = rp[nid], end = rp[nid + 1];
    float adn = ad2[nid];
    float psf = __expf(leaky(as2[nid] + adn));
    float dsum = 0.f;
    int g = lane & 7, sub = lane >> 3;
    float4 acc = make_float4(0.f, 0.f, 0.f, 0.f);
    for (int base = start; base < end; base += 64) {
        int i = base + lane;
        int sidx = 0;
        float p = 0.f;
        if (i < end) {
            sidx = col[i];
            p = __expf(leaky(as2[sidx] + adn));
            dsum += p;
        }
        int len = min(64, end - base);
        int steps = (len + 7) >> 3;
        for (int s = 0; s < steps; ++s) {
            int j = s * 8 + sub;
            int js = (j < len) ? j : 0;
            int rj = __shfl(sidx, js);
            float pj = __shfl(p, js);
            if (j < len) {
                H4 u = ((const H4*)(h2h + (size_t)rj * 32))[g];
                acc.x += (float)u.h[0].x * pj; acc.y += (float)u.h[0].y * pj;
                acc.z += (float)u.h[1].x * pj; acc.w += (float)u.h[1].y * pj;
            }
        }
    }
    if (sub == 0) {
        H4 u = ((const H4*)(h2h + (size_t)nid * 32))[g];
        acc.x += (float)u.h[0].x * psf; acc.y += (float)u.h[0].y * psf;
        acc.z += (float)u.h[1].x * psf; acc.w += (float)u.h[1].y * psf;
    }
    if (lane == 0) dsum += psf;
#pragma unroll
    for (int o = 1; o < 64; o <<= 1) dsum += __shfl_xor(dsum, o);
#pragma unroll
    for (int o = 8; o < 64; o <<= 1) {
        acc.x += __shfl_xor(acc.x, o); acc.y += __shfl_xor(acc.y, o);
        acc.z += __shfl_xor(acc.z, o); acc.w += __shfl_xor(acc.w, o);
    }
    if (sub == 0) {
        float inv = __builtin_amdgcn_rcpf(dsum);
        float4 bb = ((const float4*)b2)[g];
        ((float4*)(out + (size_t)nid * 32))[g] =
            make_float4(acc.x * inv + bb.x, acc.y * inv + bb.y,
                        acc.z * inv + bb.z, acc.w * inv + bb.w);
    }
}

// ---------------- launch ----------------

extern "C" void kernel_launch(void* const* d_in, const int* in_sizes, int n_in,
                              void* d_out, int out_size, void* d_ws, size_t ws_size,
                              hipStream_t stream) {
    const float* x      = (const float*)d_in[0];
    const int*   ei     = (const int*)d_in[1];
    const float* W1     = (const float*)d_in[2];
    const float* a_src1 = (const float*)d_in[3];
    const float* a_dst1 = (const float*)d_in[4];
    const float* b1     = (const float*)d_in[5];
    const float* W2     = (const float*)d_in[6];
    const float* a_src2 = (const float*)d_in[7];
    const float* a_dst2 = (const float*)d_in[8];
    const float* b2     = (const float*)d_in[9];
    float* out = (float*)d_out;

    const int N = in_sizes[0] / 128;
    const int E = in_sizes[1] / 2;
    const int* src = ei;
    const int* dstp = ei + E;

    uint8_t* w = (uint8_t*)d_ws;
    auto carve = [&](size_t bytes) {
        uint8_t* p = w;
        w += (bytes + 255) & ~(size_t)255;
        return p;
    };
    _Float16* h1h = (_Float16*)carve((size_t)N * 128 * 2);
    _Float16* hph = (_Float16*)carve((size_t)N * 128 * 2);
    _Float16* h2h = (_Float16*)carve((size_t)N * 32 * 2);
    float* as1 = (float*)carve((size_t)N * 4 * 4);
    float* ad1 = (float*)carve((size_t)N * 4 * 4);
    float* as2 = (float*)carve((size_t)N * 4);
    float* ad2 = (float*)carve((size_t)N * 4);
    int* rp    = (int*)carve((size_t)(N + 1) * 4);
    int* cnt   = (int*)carve((size_t)N * 4);
    int* col   = (int*)carve((size_t)E * 4);
    int* ranks = (int*)carve((size_t)E * 4);

    const int gemmBlocks = 2 * ((N + 63) / 64);
    const int countBlocks = (E + 127) / 128;

    // D1: zero counts
    hipMemsetAsync(cnt, 0, (size_t)N * 4, stream);
    // D2: gemm1 + count (independent; count atomics hide under gemm compute)
    gemm1_count_kernel<<<gemmBlocks + countBlocks, 128, 0, stream>>>(
        x, W1, a_src1, a_dst1, h1h, as1, ad1, N, gemmBlocks, dstp, cnt, ranks, E);
    // D3: scan cnt -> rp
    scan_kernel<<<1, 1024, 0, stream>>>(cnt, rp, N);
    // D4: atomic-free scatter via ranks
    scatter_kernel<<<(E + 255) / 256, 256, 0, stream>>>(src, dstp, rp, ranks, col, E);
    // D5: layer-1 aggregate
    agg1_kernel<<<(N + 3) / 4, 256, 0, stream>>>(h1h, (const float4*)as1, (const float4*)ad1,
                                                 rp, col, b1, hph, N);
    // D6: layer-2 GEMM
    gemm2_kernel<<<(N + 31) / 32, 256, 0, stream>>>(hph, W2, a_src2, a_dst2, h2h, as2, ad2, N);
    // D7: layer-2 aggregate
    agg2_kernel<<<(N + 3) / 4, 256, 0, stream>>>(h2h, as2, ad2, rp, col, b2, out, N);
}

// Round 13
// 241.248 us; speedup vs baseline: 6.9344x; 1.2815x over previous
//
#include <hip/hip_runtime.h>
#include <cstdint>

#define NEG_SLOPE 0.2f

__device__ __forceinline__ float leaky(float v) { return v > 0.f ? v : NEG_SLOPE * v; }
__device__ __forceinline__ float elu(float v) { return v > 0.f ? v : __expf(v) - 1.f; }

typedef _Float16 half2v __attribute__((ext_vector_type(2)));
union H8 { float4 f4; half2v h[4]; };   // 16 B = 8 halves
union H4 { float2 f2; half2v h[2]; };   // 8 B = 4 halves

// ---------------- parallel scan, 2 dispatches ----------------
// scanA: per-1024-chunk sums. scanC: each block redundantly scans the <=64
// chunk sums in-register (absorbs the old scanB dispatch) and writes rp.

__global__ __launch_bounds__(256) void scanA_kernel(const int* __restrict__ cnt,
                                                    int* __restrict__ bsum, int n) {
    int base = blockIdx.x * 1024 + threadIdx.x * 4;
    int s = 0;
    if (base + 3 < n) {
        int4 v = *(const int4*)(cnt + base);
        s = v.x + v.y + v.z + v.w;
    } else {
        for (int j = 0; j < 4; ++j) if (base + j < n) s += cnt[base + j];
    }
#pragma unroll
    for (int o = 1; o < 64; o <<= 1) s += __shfl_xor(s, o);
    __shared__ int ws_[4];
    if ((threadIdx.x & 63) == 0) ws_[threadIdx.x >> 6] = s;
    __syncthreads();
    if (threadIdx.x == 0) bsum[blockIdx.x] = ws_[0] + ws_[1] + ws_[2] + ws_[3];
}

// G <= 64 assumed (N <= 65536). Each block: wave 0 scans bsum in-register,
// broadcasts via LDS; then the block scans its own 1024-chunk and writes rp.
__global__ __launch_bounds__(256) void scanC_kernel(const int* __restrict__ cnt,
                                                    const int* __restrict__ bsum,
                                                    int* __restrict__ rp, int n, int G) {
    __shared__ int bpre[64];            // exclusive prefix of block sums
    int b = blockIdx.x, t = threadIdx.x;
    if (t < 64) {
        int lane = t;
        int v = (lane < G) ? bsum[lane] : 0;
        int x = v;
#pragma unroll
        for (int o = 1; o < 64; o <<= 1) { int u = __shfl_up(x, o); if (lane >= o) x += u; }
        bpre[lane] = x - v;             // exclusive
    }
    __syncthreads();
    int base = b * 1024 + t * 4;
    int v[4]; int s = 0;
#pragma unroll
    for (int j = 0; j < 4; ++j) { int idx = base + j; v[j] = (idx < n) ? cnt[idx] : 0; s += v[j]; }
    int lane = t & 63;
    int x = s;
#pragma unroll
    for (int o = 1; o < 64; o <<= 1) { int u = __shfl_up(x, o); if (lane >= o) x += u; }
    __shared__ int wsum[4], woff[4];
    if (lane == 63) wsum[t >> 6] = x;
    __syncthreads();
    if (t == 0) { int a = 0; for (int i = 0; i < 4; ++i) { woff[i] = a; a += wsum[i]; } }
    __syncthreads();
    int off = bpre[b] + (x - s) + woff[t >> 6];
#pragma unroll
    for (int j = 0; j < 4; ++j) {
        int idx = base + j;
        if (idx <= n) rp[idx] = off;
        off += v[j];
    }
}

// ---------------- scatter (rank-based, atomic-free) ----------------

__global__ void scatter_kernel(const int* __restrict__ src, const int* __restrict__ dstp,
                               const int* __restrict__ rp, const int* __restrict__ ranks,
                               int* __restrict__ col, int E) {
    int i = blockIdx.x * blockDim.x + threadIdx.x;
    if (i < E) col[rp[dstp[i]] + ranks[i]] = src[i];
}

// ---------------- fused GEMM1 + edge count ----------------
// Blocks [0, gemmBlocks): h1 = x @ W1 (fp16 out) + fused alpha dots.
// Blocks [gemmBlocks, ...): in-degree count, storing per-edge rank (atomicAdd
// return) so the scatter pass needs no atomics.

__global__ __launch_bounds__(128, 4) void gemm1_count_kernel(
        const float* __restrict__ x, const float* __restrict__ W,
        const float* __restrict__ a_src, const float* __restrict__ a_dst,
        _Float16* __restrict__ h1h, float* __restrict__ as1, float* __restrict__ ad1,
        int n, int gemmBlocks,
        const int* __restrict__ dstp, int* __restrict__ cnt, int* __restrict__ ranks, int E) {
    if ((int)blockIdx.x >= gemmBlocks) {
        int i = ((int)blockIdx.x - gemmBlocks) * 128 + threadIdx.x;
        if (i < E) ranks[i] = atomicAdd(&cnt[dstp[i]], 1);
        return;
    }
    __shared__ float xT[32 * 76];     // [k][row], row-padded to 76
    __shared__ float Wl[32 * 64];     // [k][col]
    int tid = threadIdx.x;
    int rb = blockIdx.x >> 1, cb = blockIdx.x & 1;
    int row0 = rb * 64;
    int r0 = (tid >> 4) * 8, c0 = (tid & 15) * 4;

    float4 acc[8];
#pragma unroll
    for (int r = 0; r < 8; ++r) acc[r] = make_float4(0.f, 0.f, 0.f, 0.f);

    const float4* W4 = (const float4*)W;
#pragma unroll 1
    for (int kc = 0; kc < 128; kc += 32) {
        __syncthreads();
        // stage x chunk transposed: 64 rows x 32 k
#pragma unroll
        for (int i = 0; i < 4; ++i) {
            int idx = tid + i * 128;          // float4 index: row*8 + kq
            int row = idx >> 3, kq = idx & 7;
            float4 v = make_float4(0.f, 0.f, 0.f, 0.f);
            if (row0 + row < n)
                v = *(const float4*)(x + (size_t)(row0 + row) * 128 + kc + kq * 4);
            xT[(kq * 4 + 0) * 76 + row] = v.x;
            xT[(kq * 4 + 1) * 76 + row] = v.y;
            xT[(kq * 4 + 2) * 76 + row] = v.z;
            xT[(kq * 4 + 3) * 76 + row] = v.w;
        }
        // stage W chunk: 32 k x 64 cols
#pragma unroll
        for (int i = 0; i < 4; ++i) {
            int idx = tid + i * 128;          // float4 index: k*16 + c4
            int k = idx >> 4, c4 = idx & 15;
            ((float4*)Wl)[k * 16 + c4] = W4[(kc + k) * 32 + cb * 16 + c4];
        }
        __syncthreads();
#pragma unroll 8
        for (int k = 0; k < 32; ++k) {
            float4 xa = *(float4*)&xT[k * 76 + r0];
            float4 xb = *(float4*)&xT[k * 76 + r0 + 4];
            float4 w  = *(float4*)&Wl[k * 64 + c0];
            acc[0].x += xa.x * w.x; acc[0].y += xa.x * w.y; acc[0].z += xa.x * w.z; acc[0].w += xa.x * w.w;
            acc[1].x += xa.y * w.x; acc[1].y += xa.y * w.y; acc[1].z += xa.y * w.z; acc[1].w += xa.y * w.w;
            acc[2].x += xa.z * w.x; acc[2].y += xa.z * w.y; acc[2].z += xa.z * w.z; acc[2].w += xa.z * w.w;
            acc[3].x += xa.w * w.x; acc[3].y += xa.w * w.y; acc[3].z += xa.w * w.z; acc[3].w += xa.w * w.w;
            acc[4].x += xb.x * w.x; acc[4].y += xb.x * w.y; acc[4].z += xb.x * w.z; acc[4].w += xb.x * w.w;
            acc[5].x += xb.y * w.x; acc[5].y += xb.y * w.y; acc[5].z += xb.y * w.z; acc[5].w += xb.y * w.w;
            acc[6].x += xb.z * w.x; acc[6].y += xb.z * w.y; acc[6].z += xb.z * w.z; acc[6].w += xb.z * w.w;
            acc[7].x += xb.w * w.x; acc[7].y += xb.w * w.y; acc[7].z += xb.w * w.z; acc[7].w += xb.w * w.w;
        }
    }
    // epilogue: fp16 store + fused alpha dots. global col = cb*64 + c0,
    // head h = cb*2 + (c0>>5), within-head col = c0 & 31.
    int h = cb * 2 + (c0 >> 5);
    int cc = c0 & 31;
    float asv[4], adv[4];
#pragma unroll
    for (int j = 0; j < 4; ++j) {
        asv[j] = a_src[h * 32 + cc + j];
        adv[j] = a_dst[h * 32 + cc + j];
    }
#pragma unroll
    for (int r = 0; r < 8; ++r) {
        int row = row0 + r0 + r;
        float4 a = acc[r];
        float ps = a.x * asv[0] + a.y * asv[1] + a.z * asv[2] + a.w * asv[3];
        float pd = a.x * adv[0] + a.y * adv[1] + a.z * adv[2] + a.w * adv[3];
#pragma unroll
        for (int o = 1; o < 8; o <<= 1) {
            ps += __shfl_xor(ps, o); pd += __shfl_xor(pd, o);
        }
        if (row < n) {
            H4 u;
            u.h[0] = half2v{(_Float16)a.x, (_Float16)a.y};
            u.h[1] = half2v{(_Float16)a.z, (_Float16)a.w};
            *(float2*)&h1h[(size_t)row * 128 + cb * 64 + c0] = u.f2;
            if ((tid & 7) == 0) {
                as1[row * 4 + h] = ps;
                ad1[row * 4 + h] = pd;
            }
        }
    }
}

// ---------------- GEMM2: h2 = hp @ W2 (fp16 in/out) + fused alpha dots ----------------

__global__ __launch_bounds__(256) void gemm2_kernel(const _Float16* __restrict__ hph,
                                                    const float* __restrict__ W2,
                                                    const float* __restrict__ a_src,
                                                    const float* __restrict__ a_dst,
                                                    _Float16* __restrict__ h2h,
                                                    float* __restrict__ as2,
                                                    float* __restrict__ ad2, int n) {
    __shared__ float Wl[128 * 32];
    __shared__ float xl[32][129];
    int tid = threadIdx.x;
    const float4* W4 = (const float4*)W2;
    float4* Wl4 = (float4*)Wl;
#pragma unroll
    for (int i = 0; i < 4; ++i) Wl4[tid + i * 256] = W4[tid + i * 256];
    int row0 = blockIdx.x * 32;
    for (int f = tid; f < 32 * 128; f += 256) {
        int r = f >> 7, k = f & 127;
        int row = row0 + r;
        xl[r][k] = (row < n) ? (float)hph[(size_t)row * 128 + k] : 0.f;
    }
    __syncthreads();
    int cg = tid & 7, r = tid >> 3;
    int c0 = cg * 4;
    float a0 = 0, a1 = 0, a2 = 0, a3 = 0;
    for (int k = 0; k < 128; ++k) {
        float4 w = *(const float4*)&Wl[k * 32 + c0];
        float xv = xl[r][k];
        a0 += xv * w.x; a1 += xv * w.y; a2 += xv * w.z; a3 += xv * w.w;
    }
    float ps = a0 * a_src[c0] + a1 * a_src[c0 + 1] + a2 * a_src[c0 + 2] + a3 * a_src[c0 + 3];
    float pd = a0 * a_dst[c0] + a1 * a_dst[c0 + 1] + a2 * a_dst[c0 + 2] + a3 * a_dst[c0 + 3];
#pragma unroll
    for (int o = 1; o < 8; o <<= 1) { ps += __shfl_xor(ps, o); pd += __shfl_xor(pd, o); }
    int row = row0 + r;
    if (row < n) {
        H4 u;
        u.h[0] = half2v{(_Float16)a0, (_Float16)a1};
        u.h[1] = half2v{(_Float16)a2, (_Float16)a3};
        *(float2*)&h2h[(size_t)row * 32 + c0] = u.f2;
        if (cg == 0) { as2[row] = ps; ad2[row] = pd; }
    }
}

// ---------------- layer-1 softmax + aggregate: wave/node, fp16 gather ----------------

__global__ __launch_bounds__(256) void agg1_kernel(const _Float16* __restrict__ h1h,
                                                   const float4* __restrict__ as1,
                                                   const float4* __restrict__ ad1,
                                                   const int* __restrict__ rp,
                                                   const int* __restrict__ col,
                                                   const float* __restrict__ b1,
                                                   _Float16* __restrict__ hph, int n) {
    __shared__ float4 s_p[4][64];
    int wave = threadIdx.x >> 6, lane = threadIdx.x & 63;
    int nid = blockIdx.x * 4 + wave;
    if (nid >= n) return;
    int start = rp[nid], end = rp[nid + 1];
    float4 adn = ad1[nid], asn = as1[nid];
    float4 psf;
    psf.x = __expf(leaky(asn.x + adn.x));
    psf.y = __expf(leaky(asn.y + adn.y));
    psf.z = __expf(leaky(asn.z + adn.z));
    psf.w = __expf(leaky(asn.w + adn.w));
    float4 dsum = make_float4(0.f, 0.f, 0.f, 0.f);
    int g = lane & 7, sub = lane >> 3;
    float4 aL0 = make_float4(0.f, 0.f, 0.f, 0.f);
    float4 aL1 = aL0, aH0 = aL0, aH1 = aL0;

    for (int base = start; base < end; base += 64) {
        int i = base + lane;
        int sidx = 0;
        float4 p = make_float4(0.f, 0.f, 0.f, 0.f);
        if (i < end) {
            sidx = col[i];
            float4 a = as1[sidx];
            p.x = __expf(leaky(a.x + adn.x));
            p.y = __expf(leaky(a.y + adn.y));
            p.z = __expf(leaky(a.z + adn.z));
            p.w = __expf(leaky(a.w + adn.w));
            dsum.x += p.x; dsum.y += p.y; dsum.z += p.z; dsum.w += p.w;
        }
        s_p[wave][lane] = p;         // intra-wave LDS, program order per wave
        int len = min(64, end - base);
        int steps = (len + 7) >> 3;  // wave-uniform
        for (int s = 0; s < steps; ++s) {
            int j = s * 8 + sub;
            int js = (j < len) ? j : 0;
            int rj = __shfl(sidx, js);           // all 64 lanes active
            if (j < len) {
                float4 pv = s_p[wave][js];
                float wl = (g < 4) ? pv.x : pv.y;
                float wh = (g < 4) ? pv.z : pv.w;
                const H8* row = (const H8*)(h1h + (size_t)rj * 128);
                H8 u0 = row[g], u1 = row[8 + g];
                aL0.x += (float)u0.h[0].x * wl; aL0.y += (float)u0.h[0].y * wl;
                aL0.z += (float)u0.h[1].x * wl; aL0.w += (float)u0.h[1].y * wl;
                aL1.x += (float)u0.h[2].x * wl; aL1.y += (float)u0.h[2].y * wl;
                aL1.z += (float)u0.h[3].x * wl; aL1.w += (float)u0.h[3].y * wl;
                aH0.x += (float)u1.h[0].x * wh; aH0.y += (float)u1.h[0].y * wh;
                aH0.z += (float)u1.h[1].x * wh; aH0.w += (float)u1.h[1].y * wh;
                aH1.x += (float)u1.h[2].x * wh; aH1.y += (float)u1.h[2].y * wh;
                aH1.z += (float)u1.h[3].x * wh; aH1.w += (float)u1.h[3].y * wh;
            }
        }
    }
    // self loop (one edge-subset adds it)
    if (sub == 0) {
        float wl = (g < 4) ? psf.x : psf.y;
        float wh = (g < 4) ? psf.z : psf.w;
        const H8* row = (const H8*)(h1h + (size_t)nid * 128);
        H8 u0 = row[g], u1 = row[8 + g];
        aL0.x += (float)u0.h[0].x * wl; aL0.y += (float)u0.h[0].y * wl;
        aL0.z += (float)u0.h[1].x * wl; aL0.w += (float)u0.h[1].y * wl;
        aL1.x += (float)u0.h[2].x * wl; aL1.y += (float)u0.h[2].y * wl;
        aL1.z += (float)u0.h[3].x * wl; aL1.w += (float)u0.h[3].y * wl;
        aH0.x += (float)u1.h[0].x * wh; aH0.y += (float)u1.h[0].y * wh;
        aH0.z += (float)u1.h[1].x * wh; aH0.w += (float)u1.h[1].y * wh;
        aH1.x += (float)u1.h[2].x * wh; aH1.y += (float)u1.h[2].y * wh;
        aH1.z += (float)u1.h[3].x * wh; aH1.w += (float)u1.h[3].y * wh;
    }
    if (lane == 0) {
        dsum.x += psf.x; dsum.y += psf.y; dsum.z += psf.z; dsum.w += psf.w;
    }
#pragma unroll
    for (int o = 1; o < 64; o <<= 1) {
        dsum.x += __shfl_xor(dsum.x, o); dsum.y += __shfl_xor(dsum.y, o);
        dsum.z += __shfl_xor(dsum.z, o); dsum.w += __shfl_xor(dsum.w, o);
    }
#pragma unroll
    for (int o = 8; o < 64; o <<= 1) {    // reduce over edge subsets (same g)
        aL0.x += __shfl_xor(aL0.x, o); aL0.y += __shfl_xor(aL0.y, o);
        aL0.z += __shfl_xor(aL0.z, o); aL0.w += __shfl_xor(aL0.w, o);
        aL1.x += __shfl_xor(aL1.x, o); aL1.y += __shfl_xor(aL1.y, o);
        aL1.z += __shfl_xor(aL1.z, o); aL1.w += __shfl_xor(aL1.w, o);
        aH0.x += __shfl_xor(aH0.x, o); aH0.y += __shfl_xor(aH0.y, o);
        aH0.z += __shfl_xor(aH0.z, o); aH0.w += __shfl_xor(aH0.w, o);
        aH1.x += __shfl_xor(aH1.x, o); aH1.y += __shfl_xor(aH1.y, o);
        aH1.z += __shfl_xor(aH1.z, o); aH1.w += __shfl_xor(aH1.w, o);
    }
    if (sub == 0) {
        float i0 = __builtin_amdgcn_rcpf(dsum.x);
        float i1 = __builtin_amdgcn_rcpf(dsum.y);
        float i2 = __builtin_amdgcn_rcpf(dsum.z);
        float i3 = __builtin_amdgcn_rcpf(dsum.w);
        float il = (g < 4) ? i0 : i1;
        float ih = (g < 4) ? i2 : i3;
        const float4* b4 = (const float4*)b1;
        float4 bL0 = b4[g * 2], bL1 = b4[g * 2 + 1];
        float4 bH0 = b4[16 + g * 2], bH1 = b4[16 + g * 2 + 1];
        float4 r0 = make_float4(elu(aL0.x * il + bL0.x), elu(aL0.y * il + bL0.y),
                                elu(aL0.z * il + bL0.z), elu(aL0.w * il + bL0.w));
        float4 r1 = make_float4(elu(aL1.x * il + bL1.x), elu(aL1.y * il + bL1.y),
                                elu(aL1.z * il + bL1.z), elu(aL1.w * il + bL1.w));
        float4 r2 = make_float4(elu(aH0.x * ih + bH0.x), elu(aH0.y * ih + bH0.y),
                                elu(aH0.z * ih + bH0.z), elu(aH0.w * ih + bH0.w));
        float4 r3 = make_float4(elu(aH1.x * ih + bH1.x), elu(aH1.y * ih + bH1.y),
                                elu(aH1.z * ih + bH1.z), elu(aH1.w * ih + bH1.w));
        H8 oL, oH;
        oL.h[0] = half2v{(_Float16)r0.x, (_Float16)r0.y};
        oL.h[1] = half2v{(_Float16)r0.z, (_Float16)r0.w};
        oL.h[2] = half2v{(_Float16)r1.x, (_Float16)r1.y};
        oL.h[3] = half2v{(_Float16)r1.z, (_Float16)r1.w};
        oH.h[0] = half2v{(_Float16)r2.x, (_Float16)r2.y};
        oH.h[1] = half2v{(_Float16)r2.z, (_Float16)r2.w};
        oH.h[2] = half2v{(_Float16)r3.x, (_Float16)r3.y};
        oH.h[3] = half2v{(_Float16)r3.z, (_Float16)r3.w};
        *(float4*)&hph[(size_t)nid * 128 + g * 8] = oL.f4;
        *(float4*)&hph[(size_t)nid * 128 + 64 + g * 8] = oH.f4;
    }
}

// ---------------- layer-2 softmax + aggregate: wave/node, fp16 gather ----------------

__global__ __launch_bounds__(256) void agg2_kernel(const _Float16* __restrict__ h2h,
                                                   const float* __restrict__ as2,
                                                   const float* __restrict__ ad2,
                                                   const int* __restrict__ rp,
                                                   const int* __restrict__ col,
                                                   const float* __restrict__ b2,
                                                   float* __restrict__ out, int n) {
    int wave = threadIdx.x >> 6, lane = threadIdx.x & 63;
    int nid = blockIdx.x * 4 + wave;
    if (nid >= n) return;
    int start = rp[nid], end = rp[nid + 1];
    float adn = ad2[nid];
    float psf = __expf(leaky(as2[nid] + adn));
    float dsum = 0.f;
    int g = lane & 7, sub = lane >> 3;
    float4 acc = make_float4(0.f, 0.f, 0.f, 0.f);
    for (int base = start; base < end; base += 64) {
        int i = base + lane;
        int sidx = 0;
        float p = 0.f;
        if (i < end) {
            sidx = col[i];
            p = __expf(leaky(as2[sidx] + adn));
            dsum += p;
        }
        int len = min(64, end - base);
        int steps = (len + 7) >> 3;
        for (int s = 0; s < steps; ++s) {
            int j = s * 8 + sub;
            int js = (j < len) ? j : 0;
            int rj = __shfl(sidx, js);
            float pj = __shfl(p, js);
            if (j < len) {
                H4 u = ((const H4*)(h2h + (size_t)rj * 32))[g];
                acc.x += (float)u.h[0].x * pj; acc.y += (float)u.h[0].y * pj;
                acc.z += (float)u.h[1].x * pj; acc.w += (float)u.h[1].y * pj;
            }
        }
    }
    if (sub == 0) {
        H4 u = ((const H4*)(h2h + (size_t)nid * 32))[g];
        acc.x += (float)u.h[0].x * psf; acc.y += (float)u.h[0].y * psf;
        acc.z += (float)u.h[1].x * psf; acc.w += (float)u.h[1].y * psf;
    }
    if (lane == 0) dsum += psf;
#pragma unroll
    for (int o = 1; o < 64; o <<= 1) dsum += __shfl_xor(dsum, o);
#pragma unroll
    for (int o = 8; o < 64; o <<= 1) {
        acc.x += __shfl_xor(acc.x, o); acc.y += __shfl_xor(acc.y, o);
        acc.z += __shfl_xor(acc.z, o); acc.w += __shfl_xor(acc.w, o);
    }
    if (sub == 0) {
        float inv = __builtin_amdgcn_rcpf(dsum);
        float4 bb = ((const float4*)b2)[g];
        ((float4*)(out + (size_t)nid * 32))[g] =
            make_float4(acc.x * inv + bb.x, acc.y * inv + bb.y,
                        acc.z * inv + bb.z, acc.w * inv + bb.w);
    }
}

// ---------------- launch ----------------

extern "C" void kernel_launch(void* const* d_in, const int* in_sizes, int n_in,
                              void* d_out, int out_size, void* d_ws, size_t ws_size,
                              hipStream_t stream) {
    const float* x      = (const float*)d_in[0];
    const int*   ei     = (const int*)d_in[1];
    const float* W1     = (const float*)d_in[2];
    const float* a_src1 = (const float*)d_in[3];
    const float* a_dst1 = (const float*)d_in[4];
    const float* b1     = (const float*)d_in[5];
    const float* W2     = (const float*)d_in[6];
    const float* a_src2 = (const float*)d_in[7];
    const float* a_dst2 = (const float*)d_in[8];
    const float* b2     = (const float*)d_in[9];
    float* out = (float*)d_out;

    const int N = in_sizes[0] / 128;
    const int E = in_sizes[1] / 2;
    const int* src = ei;
    const int* dstp = ei + E;

    uint8_t* w = (uint8_t*)d_ws;
    auto carve = [&](size_t bytes) {
        uint8_t* p = w;
        w += (bytes + 255) & ~(size_t)255;
        return p;
    };
    _Float16* h1h = (_Float16*)carve((size_t)N * 128 * 2);
    _Float16* hph = (_Float16*)carve((size_t)N * 128 * 2);
    _Float16* h2h = (_Float16*)carve((size_t)N * 32 * 2);
    float* as1 = (float*)carve((size_t)N * 4 * 4);
    float* ad1 = (float*)carve((size_t)N * 4 * 4);
    float* as2 = (float*)carve((size_t)N * 4);
    float* ad2 = (float*)carve((size_t)N * 4);
    int* rp    = (int*)carve((size_t)(N + 1) * 4);
    int* cnt   = (int*)carve((size_t)N * 4);
    int* col   = (int*)carve((size_t)E * 4);
    int* ranks = (int*)carve((size_t)E * 4);
    int* bsum  = (int*)carve(64 * 4);

    const int gemmBlocks = 2 * ((N + 63) / 64);
    const int countBlocks = (E + 127) / 128;
    const int G = (N + 1023) / 1024;   // <= 64 for N <= 65536

    // D1: zero counts
    hipMemsetAsync(cnt, 0, (size_t)N * 4, stream);
    // D2: gemm1 + count (independent; count atomics hide under gemm compute)
    gemm1_count_kernel<<<gemmBlocks + countBlocks, 128, 0, stream>>>(
        x, W1, a_src1, a_dst1, h1h, as1, ad1, N, gemmBlocks, dstp, cnt, ranks, E);
    // D3/D4: parallel scan cnt -> rp
    scanA_kernel<<<G, 256, 0, stream>>>(cnt, bsum, N);
    scanC_kernel<<<G, 256, 0, stream>>>(cnt, bsum, rp, N, G);
    // D5: atomic-free scatter via ranks
    scatter_kernel<<<(E + 255) / 256, 256, 0, stream>>>(src, dstp, rp, ranks, col, E);
    // D6: layer-1 aggregate
    agg1_kernel<<<(N + 3) / 4, 256, 0, stream>>>(h1h, (const float4*)as1, (const float4*)ad1,
                                                 rp, col, b1, hph, N);
    // D7: layer-2 GEMM
    gemm2_kernel<<<(N + 31) / 32, 256, 0, stream>>>(hph, W2, a_src2, a_dst2, h2h, as2, ad2, N);
    // D8: layer-2 aggregate
    agg2_kernel<<<(N + 3) / 4, 256, 0, stream>>>(h2h, as2, ad2, rp, col, b2, out, N);
}

// Round 14
// 237.094 us; speedup vs baseline: 7.0559x; 1.0175x over previous
//
#include <hip/hip_runtime.h>
#include <cstdint>

#define NEG_SLOPE 0.2f

__device__ __forceinline__ float leaky(float v) { return v > 0.f ? v : NEG_SLOPE * v; }
__device__ __forceinline__ float elu(float v) { return v > 0.f ? v : __expf(v) - 1.f; }

typedef _Float16 half2v __attribute__((ext_vector_type(2)));
union H8 { float4 f4; half2v h[4]; };   // 16 B = 8 halves
union H4 { float2 f2; half2v h[2]; };   // 8 B = 4 halves

// ---------------- parallel scan, 2 dispatches ----------------

__global__ __launch_bounds__(256) void scanA_kernel(const int* __restrict__ cnt,
                                                    int* __restrict__ bsum, int n) {
    int base = blockIdx.x * 1024 + threadIdx.x * 4;
    int s = 0;
    if (base + 3 < n) {
        int4 v = *(const int4*)(cnt + base);
        s = v.x + v.y + v.z + v.w;
    } else {
        for (int j = 0; j < 4; ++j) if (base + j < n) s += cnt[base + j];
    }
#pragma unroll
    for (int o = 1; o < 64; o <<= 1) s += __shfl_xor(s, o);
    __shared__ int ws_[4];
    if ((threadIdx.x & 63) == 0) ws_[threadIdx.x >> 6] = s;
    __syncthreads();
    if (threadIdx.x == 0) bsum[blockIdx.x] = ws_[0] + ws_[1] + ws_[2] + ws_[3];
}

// G <= 64 assumed (N <= 65536). Each block: wave 0 scans bsum in-register,
// broadcasts via LDS; then the block scans its own 1024-chunk and writes rp.
__global__ __launch_bounds__(256) void scanC_kernel(const int* __restrict__ cnt,
                                                    const int* __restrict__ bsum,
                                                    int* __restrict__ rp, int n, int G) {
    __shared__ int bpre[64];            // exclusive prefix of block sums
    int b = blockIdx.x, t = threadIdx.x;
    if (t < 64) {
        int lane = t;
        int v = (lane < G) ? bsum[lane] : 0;
        int x = v;
#pragma unroll
        for (int o = 1; o < 64; o <<= 1) { int u = __shfl_up(x, o); if (lane >= o) x += u; }
        bpre[lane] = x - v;             // exclusive
    }
    __syncthreads();
    int base = b * 1024 + t * 4;
    int v[4]; int s = 0;
#pragma unroll
    for (int j = 0; j < 4; ++j) { int idx = base + j; v[j] = (idx < n) ? cnt[idx] : 0; s += v[j]; }
    int lane = t & 63;
    int x = s;
#pragma unroll
    for (int o = 1; o < 64; o <<= 1) { int u = __shfl_up(x, o); if (lane >= o) x += u; }
    __shared__ int wsum[4], woff[4];
    if (lane == 63) wsum[t >> 6] = x;
    __syncthreads();
    if (t == 0) { int a = 0; for (int i = 0; i < 4; ++i) { woff[i] = a; a += wsum[i]; } }
    __syncthreads();
    int off = bpre[b] + (x - s) + woff[t >> 6];
#pragma unroll
    for (int j = 0; j < 4; ++j) {
        int idx = base + j;
        if (idx <= n) rp[idx] = off;
        off += v[j];
    }
}

// ---------------- scatter (rank-based, atomic-free) ----------------

__global__ void scatter_kernel(const int* __restrict__ src, const int* __restrict__ dstp,
                               const int* __restrict__ rp, const int* __restrict__ ranks,
                               int* __restrict__ col, int E) {
    int i = blockIdx.x * blockDim.x + threadIdx.x;
    if (i < E) col[rp[dstp[i]] + ranks[i]] = src[i];
}

// ---------------- fused GEMM1 + edge count ----------------

__global__ __launch_bounds__(128, 4) void gemm1_count_kernel(
        const float* __restrict__ x, const float* __restrict__ W,
        const float* __restrict__ a_src, const float* __restrict__ a_dst,
        _Float16* __restrict__ h1h, float* __restrict__ as1, float* __restrict__ ad1,
        int n, int gemmBlocks,
        const int* __restrict__ dstp, int* __restrict__ cnt, int* __restrict__ ranks, int E) {
    if ((int)blockIdx.x >= gemmBlocks) {
        int i = ((int)blockIdx.x - gemmBlocks) * 128 + threadIdx.x;
        if (i < E) ranks[i] = atomicAdd(&cnt[dstp[i]], 1);
        return;
    }
    __shared__ float xT[32 * 76];     // [k][row], row-padded to 76
    __shared__ float Wl[32 * 64];     // [k][col]
    int tid = threadIdx.x;
    int rb = blockIdx.x >> 1, cb = blockIdx.x & 1;
    int row0 = rb * 64;
    int r0 = (tid >> 4) * 8, c0 = (tid & 15) * 4;

    float4 acc[8];
#pragma unroll
    for (int r = 0; r < 8; ++r) acc[r] = make_float4(0.f, 0.f, 0.f, 0.f);

    const float4* W4 = (const float4*)W;
#pragma unroll 1
    for (int kc = 0; kc < 128; kc += 32) {
        __syncthreads();
#pragma unroll
        for (int i = 0; i < 4; ++i) {
            int idx = tid + i * 128;          // float4 index: row*8 + kq
            int row = idx >> 3, kq = idx & 7;
            float4 v = make_float4(0.f, 0.f, 0.f, 0.f);
            if (row0 + row < n)
                v = *(const float4*)(x + (size_t)(row0 + row) * 128 + kc + kq * 4);
            xT[(kq * 4 + 0) * 76 + row] = v.x;
            xT[(kq * 4 + 1) * 76 + row] = v.y;
            xT[(kq * 4 + 2) * 76 + row] = v.z;
            xT[(kq * 4 + 3) * 76 + row] = v.w;
        }
#pragma unroll
        for (int i = 0; i < 4; ++i) {
            int idx = tid + i * 128;          // float4 index: k*16 + c4
            int k = idx >> 4, c4 = idx & 15;
            ((float4*)Wl)[k * 16 + c4] = W4[(kc + k) * 32 + cb * 16 + c4];
        }
        __syncthreads();
#pragma unroll 8
        for (int k = 0; k < 32; ++k) {
            float4 xa = *(float4*)&xT[k * 76 + r0];
            float4 xb = *(float4*)&xT[k * 76 + r0 + 4];
            float4 w  = *(float4*)&Wl[k * 64 + c0];
            acc[0].x += xa.x * w.x; acc[0].y += xa.x * w.y; acc[0].z += xa.x * w.z; acc[0].w += xa.x * w.w;
            acc[1].x += xa.y * w.x; acc[1].y += xa.y * w.y; acc[1].z += xa.y * w.z; acc[1].w += xa.y * w.w;
            acc[2].x += xa.z * w.x; acc[2].y += xa.z * w.y; acc[2].z += xa.z * w.z; acc[2].w += xa.z * w.w;
            acc[3].x += xa.w * w.x; acc[3].y += xa.w * w.y; acc[3].z += xa.w * w.z; acc[3].w += xa.w * w.w;
            acc[4].x += xb.x * w.x; acc[4].y += xb.x * w.y; acc[4].z += xb.x * w.z; acc[4].w += xb.x * w.w;
            acc[5].x += xb.y * w.x; acc[5].y += xb.y * w.y; acc[5].z += xb.y * w.z; acc[5].w += xb.y * w.w;
            acc[6].x += xb.z * w.x; acc[6].y += xb.z * w.y; acc[6].z += xb.z * w.z; acc[6].w += xb.z * w.w;
            acc[7].x += xb.w * w.x; acc[7].y += xb.w * w.y; acc[7].z += xb.w * w.z; acc[7].w += xb.w * w.w;
        }
    }
    int h = cb * 2 + (c0 >> 5);
    int cc = c0 & 31;
    float asv[4], adv[4];
#pragma unroll
    for (int j = 0; j < 4; ++j) {
        asv[j] = a_src[h * 32 + cc + j];
        adv[j] = a_dst[h * 32 + cc + j];
    }
#pragma unroll
    for (int r = 0; r < 8; ++r) {
        int row = row0 + r0 + r;
        float4 a = acc[r];
        float ps = a.x * asv[0] + a.y * asv[1] + a.z * asv[2] + a.w * asv[3];
        float pd = a.x * adv[0] + a.y * adv[1] + a.z * adv[2] + a.w * adv[3];
#pragma unroll
        for (int o = 1; o < 8; o <<= 1) {
            ps += __shfl_xor(ps, o); pd += __shfl_xor(pd, o);
        }
        if (row < n) {
            H4 u;
            u.h[0] = half2v{(_Float16)a.x, (_Float16)a.y};
            u.h[1] = half2v{(_Float16)a.z, (_Float16)a.w};
            *(float2*)&h1h[(size_t)row * 128 + cb * 64 + c0] = u.f2;
            if ((tid & 7) == 0) {
                as1[row * 4 + h] = ps;
                ad1[row * 4 + h] = pd;
            }
        }
    }
}

// ---------------- GEMM2: h2 = hp @ W2 (fp16 in/out) + fused alpha dots ----------------

__global__ __launch_bounds__(256) void gemm2_kernel(const _Float16* __restrict__ hph,
                                                    const float* __restrict__ W2,
                                                    const float* __restrict__ a_src,
                                                    const float* __restrict__ a_dst,
                                                    _Float16* __restrict__ h2h,
                                                    float* __restrict__ as2,
                                                    float* __restrict__ ad2, int n) {
    __shared__ float Wl[128 * 32];
    __shared__ float xl[32][129];
    int tid = threadIdx.x;
    const float4* W4 = (const float4*)W2;
    float4* Wl4 = (float4*)Wl;
#pragma unroll
    for (int i = 0; i < 4; ++i) Wl4[tid + i * 256] = W4[tid + i * 256];
    int row0 = blockIdx.x * 32;
    for (int f = tid; f < 32 * 128; f += 256) {
        int r = f >> 7, k = f & 127;
        int row = row0 + r;
        xl[r][k] = (row < n) ? (float)hph[(size_t)row * 128 + k] : 0.f;
    }
    __syncthreads();
    int cg = tid & 7, r = tid >> 3;
    int c0 = cg * 4;
    float a0 = 0, a1 = 0, a2 = 0, a3 = 0;
    for (int k = 0; k < 128; ++k) {
        float4 w = *(const float4*)&Wl[k * 32 + c0];
        float xv = xl[r][k];
        a0 += xv * w.x; a1 += xv * w.y; a2 += xv * w.z; a3 += xv * w.w;
    }
    float ps = a0 * a_src[c0] + a1 * a_src[c0 + 1] + a2 * a_src[c0 + 2] + a3 * a_src[c0 + 3];
    float pd = a0 * a_dst[c0] + a1 * a_dst[c0 + 1] + a2 * a_dst[c0 + 2] + a3 * a_dst[c0 + 3];
#pragma unroll
    for (int o = 1; o < 8; o <<= 1) { ps += __shfl_xor(ps, o); pd += __shfl_xor(pd, o); }
    int row = row0 + r;
    if (row < n) {
        H4 u;
        u.h[0] = half2v{(_Float16)a0, (_Float16)a1};
        u.h[1] = half2v{(_Float16)a2, (_Float16)a3};
        *(float2*)&h2h[(size_t)row * 32 + c0] = u.f2;
        if (cg == 0) { as2[row] = ps; ad2[row] = pd; }
    }
}

// ---------------- layer-1 softmax + aggregate: wave/node, fp16 gather ----------------
// Round-14 re-shape: 16 channel-groups (8 ch = one H8 per lane) x 4 edge-subsets.
// Fixed per-node cost drops: acc reduce 96->32 instrs (2 xor rounds over 4 subs),
// epilogue halves (8 ch/lane, 1 rcp), one 16B load per lane per step (16 lanes
// of a sub-group cover a full 256 B row, coalesced).

__global__ __launch_bounds__(256) void agg1_kernel(const _Float16* __restrict__ h1h,
                                                   const float4* __restrict__ as1,
                                                   const float4* __restrict__ ad1,
                                                   const int* __restrict__ rp,
                                                   const int* __restrict__ col,
                                                   const float* __restrict__ b1,
                                                   _Float16* __restrict__ hph, int n) {
    __shared__ float4 s_p[4][64];
    int wave = threadIdx.x >> 6, lane = threadIdx.x & 63;
    int nid = blockIdx.x * 4 + wave;
    if (nid >= n) return;
    int start = rp[nid], end = rp[nid + 1];
    float4 adn = ad1[nid], asn = as1[nid];
    float4 psf;
    psf.x = __expf(leaky(asn.x + adn.x));
    psf.y = __expf(leaky(asn.y + adn.y));
    psf.z = __expf(leaky(asn.z + adn.z));
    psf.w = __expf(leaky(asn.w + adn.w));
    float4 dsum = make_float4(0.f, 0.f, 0.f, 0.f);
    int g = lane & 15, sub = lane >> 4;   // g: 8-ch group, sub: edge subset
    int head = g >> 2;                    // channels g*8..g*8+7 lie in head g/4
    float4 a0 = make_float4(0.f, 0.f, 0.f, 0.f);
    float4 a1 = a0;                       // 8 fp32 accs for ch [g*8, g*8+8)

    for (int base = start; base < end; base += 64) {
        int i = base + lane;
        int sidx = 0;
        float4 p = make_float4(0.f, 0.f, 0.f, 0.f);
        if (i < end) {
            sidx = col[i];
            float4 a = as1[sidx];
            p.x = __expf(leaky(a.x + adn.x));
            p.y = __expf(leaky(a.y + adn.y));
            p.z = __expf(leaky(a.z + adn.z));
            p.w = __expf(leaky(a.w + adn.w));
            dsum.x += p.x; dsum.y += p.y; dsum.z += p.z; dsum.w += p.w;
        }
        s_p[wave][lane] = p;              // intra-wave LDS, program order per wave
        int len = min(64, end - base);
        int steps = (len + 3) >> 2;       // wave-uniform; 4 edges per step
        for (int s = 0; s < steps; ++s) {
            int j = s * 4 + sub;
            int js = (j < len) ? j : 0;
            int rj = __shfl(sidx, js);    // all 64 lanes active
            if (j < len) {
                float pj = ((const float*)&s_p[wave][js])[head];
                H8 u = ((const H8*)(h1h + (size_t)rj * 128))[g];
                a0.x += (float)u.h[0].x * pj; a0.y += (float)u.h[0].y * pj;
                a0.z += (float)u.h[1].x * pj; a0.w += (float)u.h[1].y * pj;
                a1.x += (float)u.h[2].x * pj; a1.y += (float)u.h[2].y * pj;
                a1.z += (float)u.h[3].x * pj; a1.w += (float)u.h[3].y * pj;
            }
        }
    }
    // self loop (one edge-subset adds it)
    if (sub == 0) {
        float pj = (head == 0) ? psf.x : (head == 1) ? psf.y : (head == 2) ? psf.z : psf.w;
        H8 u = ((const H8*)(h1h + (size_t)nid * 128))[g];
        a0.x += (float)u.h[0].x * pj; a0.y += (float)u.h[0].y * pj;
        a0.z += (float)u.h[1].x * pj; a0.w += (float)u.h[1].y * pj;
        a1.x += (float)u.h[2].x * pj; a1.y += (float)u.h[2].y * pj;
        a1.z += (float)u.h[3].x * pj; a1.w += (float)u.h[3].y * pj;
    }
    if (lane == 0) {
        dsum.x += psf.x; dsum.y += psf.y; dsum.z += psf.z; dsum.w += psf.w;
    }
#pragma unroll
    for (int o = 1; o < 64; o <<= 1) {
        dsum.x += __shfl_xor(dsum.x, o); dsum.y += __shfl_xor(dsum.y, o);
        dsum.z += __shfl_xor(dsum.z, o); dsum.w += __shfl_xor(dsum.w, o);
    }
#pragma unroll
    for (int o = 16; o < 64; o <<= 1) {   // reduce over 4 edge subsets (same g)
        a0.x += __shfl_xor(a0.x, o); a0.y += __shfl_xor(a0.y, o);
        a0.z += __shfl_xor(a0.z, o); a0.w += __shfl_xor(a0.w, o);
        a1.x += __shfl_xor(a1.x, o); a1.y += __shfl_xor(a1.y, o);
        a1.z += __shfl_xor(a1.z, o); a1.w += __shfl_xor(a1.w, o);
    }
    if (sub == 0) {
        float den = (head == 0) ? dsum.x : (head == 1) ? dsum.y : (head == 2) ? dsum.z : dsum.w;
        float inv = __builtin_amdgcn_rcpf(den);
        const float4* b4 = (const float4*)b1;
        float4 bb0 = b4[g * 2], bb1 = b4[g * 2 + 1];
        float4 r0 = make_float4(elu(a0.x * inv + bb0.x), elu(a0.y * inv + bb0.y),
                                elu(a0.z * inv + bb0.z), elu(a0.w * inv + bb0.w));
        float4 r1 = make_float4(elu(a1.x * inv + bb1.x), elu(a1.y * inv + bb1.y),
                                elu(a1.z * inv + bb1.z), elu(a1.w * inv + bb1.w));
        H8 o8;
        o8.h[0] = half2v{(_Float16)r0.x, (_Float16)r0.y};
        o8.h[1] = half2v{(_Float16)r0.z, (_Float16)r0.w};
        o8.h[2] = half2v{(_Float16)r1.x, (_Float16)r1.y};
        o8.h[3] = half2v{(_Float16)r1.z, (_Float16)r1.w};
        *(float4*)&hph[(size_t)nid * 128 + g * 8] = o8.f4;
    }
}

// ---------------- layer-2 softmax + aggregate: wave/node, fp16 gather ----------------

__global__ __launch_bounds__(256) void agg2_kernel(const _Float16* __restrict__ h2h,
                                                   const float* __restrict__ as2,
                                                   const float* __restrict__ ad2,
                                                   const int* __restrict__ rp,
                                                   const int* __restrict__ col,
                                                   const float* __restrict__ b2,
                                                   float* __restrict__ out, int n) {
    int wave = threadIdx.x >> 6, lane = threadIdx.x & 63;
    int nid = blockIdx.x * 4 + wave;
    if (nid >= n) return;
    int start = rp[nid], end = rp[nid + 1];
    float adn = ad2[nid];
    float psf = __expf(leaky(as2[nid] + adn));
    float dsum = 0.f;
    int g = lane & 7, sub = lane >> 3;
    float4 acc = make_float4(0.f, 0.f, 0.f, 0.f);
    for (int base = start; base < end; base += 64) {
        int i = base + lane;
        int sidx = 0;
        float p = 0.f;
        if (i < end) {
            sidx = col[i];
            p = __expf(leaky(as2[sidx] + adn));
            dsum += p;
        }
        int len = min(64, end - base);
        int steps = (len + 7) >> 3;
        for (int s = 0; s < steps; ++s) {
            int j = s * 8 + sub;
            int js = (j < len) ? j : 0;
            int rj = __shfl(sidx, js);
            float pj = __shfl(p, js);
            if (j < len) {
                H4 u = ((const H4*)(h2h + (size_t)rj * 32))[g];
                acc.x += (float)u.h[0].x * pj; acc.y += (float)u.h[0].y * pj;
                acc.z += (float)u.h[1].x * pj; acc.w += (float)u.h[1].y * pj;
            }
        }
    }
    if (sub == 0) {
        H4 u = ((const H4*)(h2h + (size_t)nid * 32))[g];
        acc.x += (float)u.h[0].x * psf; acc.y += (float)u.h[0].y * psf;
        acc.z += (float)u.h[1].x * psf; acc.w += (float)u.h[1].y * psf;
    }
    if (lane == 0) dsum += psf;
#pragma unroll
    for (int o = 1; o < 64; o <<= 1) dsum += __shfl_xor(dsum, o);
#pragma unroll
    for (int o = 8; o < 64; o <<= 1) {
        acc.x += __shfl_xor(acc.x, o); acc.y += __shfl_xor(acc.y, o);
        acc.z += __shfl_xor(acc.z, o); acc.w += __shfl_xor(acc.w, o);
    }
    if (sub == 0) {
        float inv = __builtin_amdgcn_rcpf(dsum);
        float4 bb = ((const float4*)b2)[g];
        ((float4*)(out + (size_t)nid * 32))[g] =
            make_float4(acc.x * inv + bb.x, acc.y * inv + bb.y,
                        acc.z * inv + bb.z, acc.w * inv + bb.w);
    }
}

// ---------------- launch ----------------

extern "C" void kernel_launch(void* const* d_in, const int* in_sizes, int n_in,
                              void* d_out, int out_size, void* d_ws, size_t ws_size,
                              hipStream_t stream) {
    const float* x      = (const float*)d_in[0];
    const int*   ei     = (const int*)d_in[1];
    const float* W1     = (const float*)d_in[2];
    const float* a_src1 = (const float*)d_in[3];
    const float* a_dst1 = (const float*)d_in[4];
    const float* b1     = (const float*)d_in[5];
    const float* W2     = (const float*)d_in[6];
    const float* a_src2 = (const float*)d_in[7];
    const float* a_dst2 = (const float*)d_in[8];
    const float* b2     = (const float*)d_in[9];
    float* out = (float*)d_out;

    const int N = in_sizes[0] / 128;
    const int E = in_sizes[1] / 2;
    const int* src = ei;
    const int* dstp = ei + E;

    uint8_t* w = (uint8_t*)d_ws;
    auto carve = [&](size_t bytes) {
        uint8_t* p = w;
        w += (bytes + 255) & ~(size_t)255;
        return p;
    };
    _Float16* h1h = (_Float16*)carve((size_t)N * 128 * 2);
    _Float16* hph = (_Float16*)carve((size_t)N * 128 * 2);
    _Float16* h2h = (_Float16*)carve((size_t)N * 32 * 2);
    float* as1 = (float*)carve((size_t)N * 4 * 4);
    float* ad1 = (float*)carve((size_t)N * 4 * 4);
    float* as2 = (float*)carve((size_t)N * 4);
    float* ad2 = (float*)carve((size_t)N * 4);
    int* rp    = (int*)carve((size_t)(N + 1) * 4);
    int* cnt   = (int*)carve((size_t)N * 4);
    int* col   = (int*)carve((size_t)E * 4);
    int* ranks = (int*)carve((size_t)E * 4);
    int* bsum  = (int*)carve(64 * 4);

    const int gemmBlocks = 2 * ((N + 63) / 64);
    const int countBlocks = (E + 127) / 128;
    const int G = (N + 1023) / 1024;   // <= 64 for N <= 65536

    // D1: zero counts
    hipMemsetAsync(cnt, 0, (size_t)N * 4, stream);
    // D2: gemm1 + count (independent; count atomics hide under gemm compute)
    gemm1_count_kernel<<<gemmBlocks + countBlocks, 128, 0, stream>>>(
        x, W1, a_src1, a_dst1, h1h, as1, ad1, N, gemmBlocks, dstp, cnt, ranks, E);
    // D3/D4: parallel scan cnt -> rp
    scanA_kernel<<<G, 256, 0, stream>>>(cnt, bsum, N);
    scanC_kernel<<<G, 256, 0, stream>>>(cnt, bsum, rp, N, G);
    // D5: atomic-free scatter via ranks
    scatter_kernel<<<(E + 255) / 256, 256, 0, stream>>>(src, dstp, rp, ranks, col, E);
    // D6: layer-1 aggregate
    agg1_kernel<<<(N + 3) / 4, 256, 0, stream>>>(h1h, (const float4*)as1, (const float4*)ad1,
                                                 rp, col, b1, hph, N);
    // D7: layer-2 GEMM
    gemm2_kernel<<<(N + 31) / 32, 256, 0, stream>>>(hph, W2, a_src2, a_dst2, h2h, as2, ad2, N);
    // D8: layer-2 aggregate
    agg2_kernel<<<(N + 3) / 4, 256, 0, stream>>>(h2h, as2, ad2, rp, col, b2, out, N);
}